// Round 22
// baseline (111.687 us; speedup 1.0000x reference)
//
#include <hip/hip_runtime.h>
#include <math.h>

#define N 4096
#define NFEAT 512
#define NHID 64
#define NCLASS 16
#define NHEADS 8
#define ALPHA 0.2f
#define JSPL 8            // layer-2 j-split
#define JLEN (N / JSPL)   // 512
#define HSTR 520          // layer-2 hsT row stride (ushorts)
#define J1 256            // layer-1 j sub-chunk
#define KUSTR 257         // layer-1 k-major unit stride (dwords); odd -> 2-way banks
#define JSPL1 2           // layer-1 j-split (8 chunks each)

typedef __attribute__((ext_vector_type(8))) short bf16x8;
typedef __attribute__((ext_vector_type(4))) float f32x4;

__device__ inline unsigned short f2bf(float f) {
  unsigned u = __float_as_uint(f);
  unsigned r = u + 0x7fffu + ((u >> 16) & 1u);  // RNE
  return (unsigned short)(r >> 16);
}
__device__ inline unsigned mono(float f) {
  unsigned u = __float_as_uint(f);
  return (u & 0x80000000u) ? ~u : (u | 0x80000000u);
}
__device__ inline float unmono(unsigned m) {
  return (m >> 31) ? __uint_as_float(m & 0x7FFFFFFFu) : __uint_as_float(~m);
}

// ---------------------------------------------------------------------------
// P0: pack. blocks [0,2048): x->bf16; [2048,2112): Wt=bf16(Wh^T);
// 2112: Wt2 + tmax inits.
// ---------------------------------------------------------------------------
__global__ __launch_bounds__(256) void k_pack(const float* __restrict__ x,
                                              const float* __restrict__ Wh,
                                              const float* __restrict__ Wo,
                                              unsigned short* __restrict__ xb,
                                              unsigned short* __restrict__ Wt,
                                              unsigned short* __restrict__ Wt2,
                                              unsigned* __restrict__ tmax1u,
                                              unsigned* __restrict__ tmax2u) {
  int b = blockIdx.x;
  if (b < 2048) {
    int i = (b * 256 + threadIdx.x) * 4;
    float4 v = *(const float4*)(x + i);
    ushort4 o;
    o.x = f2bf(v.x); o.y = f2bf(v.y); o.z = f2bf(v.z); o.w = f2bf(v.w);
    *(ushort4*)(xb + i) = o;
  } else if (b < 2112) {
    int idx = b - 2048;
    int kt = idx & 7, hd = idx >> 3;
    __shared__ float ld[64][65];
    const float* src = Wh + ((size_t)hd * NFEAT + kt * 64) * NHID;
    int r = threadIdx.x >> 2, c0 = (threadIdx.x & 3) * 16;
#pragma unroll
    for (int j = 0; j < 4; ++j) {
      float4 v = *(const float4*)(src + (size_t)r * NHID + c0 + j * 4);
      ld[r][c0 + j * 4 + 0] = v.x; ld[r][c0 + j * 4 + 1] = v.y;
      ld[r][c0 + j * 4 + 2] = v.z; ld[r][c0 + j * 4 + 3] = v.w;
    }
    __syncthreads();
    int n = threadIdx.x >> 2, kq = threadIdx.x & 3;
    unsigned short tmp[16];
#pragma unroll
    for (int j = 0; j < 16; ++j) tmp[j] = f2bf(ld[kq * 16 + j][n]);
    unsigned short* dst = Wt + ((size_t)hd * 64 + n) * NFEAT + kt * 64 + kq * 16;
    ((uint4*)dst)[0] = *(uint4*)tmp;
    ((uint4*)dst)[1] = *(uint4*)(tmp + 8);
  } else {
    for (int e = threadIdx.x; e < NFEAT * NCLASS; e += 256) {
      int n = e & 15, k = e >> 4;
      Wt2[(size_t)n * NFEAT + k] = f2bf(Wo[(size_t)k * NCLASS + n]);
    }
    if (threadIdx.x < NHEADS) tmax1u[threadIdx.x] = 0u;  // mono(-inf)
    if (threadIdx.x == 0) *tmax2u = 0u;
  }
}

// ---------------------------------------------------------------------------
// K1: MFMA bf16 GEMM h = x @ Wh per head, 128x64 tile, 4 waves, fused scores
// + per-head tmax. h written TRANSPOSED: h1T[hd][d][j] (bf16).
// ---------------------------------------------------------------------------
__global__ __launch_bounds__(256) void k_gemm_h(const unsigned short* __restrict__ xb,
                                                const unsigned short* __restrict__ Wt,
                                                const float* __restrict__ ah,
                                                unsigned short* __restrict__ h1T,
                                                float* __restrict__ ssrc,
                                                float* __restrict__ sdst,
                                                unsigned* __restrict__ tmax1u) {
  const int hd = blockIdx.y;
  const int i0 = blockIdx.x * 128;
  const int t = threadIdx.x;
  const int w = t >> 6, lane = t & 63;
  const int lr = lane & 15, kg = lane >> 4;
  const int wm = (w & 1) * 64, wn = (w >> 1) * 32;
  __shared__ uint4 Als[128][4];
  __shared__ uint4 Bls[64][4];
  __shared__ float sredS[128][2];
  __shared__ float sredD[128][2];
  const unsigned short* xrow = xb + (size_t)i0 * NFEAT;
  const unsigned short* wrow = Wt + (size_t)hd * 64 * NFEAT;

  f32x4 acc[4][2];
#pragma unroll
  for (int a = 0; a < 4; ++a)
#pragma unroll
    for (int b = 0; b < 2; ++b) acc[a][b] = (f32x4){0.f, 0.f, 0.f, 0.f};

  const int u0 = t, u1 = t + 256;
  const int ra0 = u0 >> 2, sa0 = ((u0 & 3) ^ (ra0 & 3)) * 8;
  const int ra1 = u1 >> 2, sa1 = ((u1 & 3) ^ (ra1 & 3)) * 8;
  const int rb0 = t >> 2,  sb0 = ((t & 3) ^ (rb0 & 3)) * 8;
  const int wbase = t & ~63;

  for (int k0 = 0; k0 < NFEAT; k0 += 32) {
    __builtin_amdgcn_global_load_lds(
        (const __attribute__((address_space(1))) void*)(xrow + (size_t)ra0 * NFEAT + k0 + sa0),
        (__attribute__((address_space(3))) void*)((uint4*)Als + wbase), 16, 0, 0);
    __builtin_amdgcn_global_load_lds(
        (const __attribute__((address_space(1))) void*)(xrow + (size_t)ra1 * NFEAT + k0 + sa1),
        (__attribute__((address_space(3))) void*)((uint4*)Als + 256 + wbase), 16, 0, 0);
    __builtin_amdgcn_global_load_lds(
        (const __attribute__((address_space(1))) void*)(wrow + (size_t)rb0 * NFEAT + k0 + sb0),
        (__attribute__((address_space(3))) void*)((uint4*)Bls + wbase), 16, 0, 0);
    __syncthreads();
    bf16x8 af[4], bfv[2];
#pragma unroll
    for (int mb = 0; mb < 4; ++mb) {
      int row = wm + mb * 16 + lr;
      af[mb] = __builtin_bit_cast(bf16x8, Als[row][kg ^ (row & 3)]);
    }
#pragma unroll
    for (int nb = 0; nb < 2; ++nb) {
      int col = wn + nb * 16 + lr;
      bfv[nb] = __builtin_bit_cast(bf16x8, Bls[col][kg ^ (col & 3)]);
    }
#pragma unroll
    for (int mb = 0; mb < 4; ++mb)
#pragma unroll
      for (int nb = 0; nb < 2; ++nb)
        acc[mb][nb] = __builtin_amdgcn_mfma_f32_16x16x32_bf16(af[mb], bfv[nb], acc[mb][nb], 0, 0, 0);
    __syncthreads();
  }

  unsigned short* hT = h1T + (size_t)hd * NHID * N;
#pragma unroll
  for (int mb = 0; mb < 4; ++mb)
#pragma unroll
    for (int nb = 0; nb < 2; ++nb) {
      int col = wn + nb * 16 + lr;
      int rbase = i0 + wm + mb * 16 + kg * 4;
      ushort4 o;
      o.x = f2bf(acc[mb][nb][0]); o.y = f2bf(acc[mb][nb][1]);
      o.z = f2bf(acc[mb][nb][2]); o.w = f2bf(acc[mb][nb][3]);
      *(ushort4*)(hT + (size_t)col * N + rbase) = o;
    }

  float aS[2], aD[2];
#pragma unroll
  for (int nb = 0; nb < 2; ++nb) {
    aS[nb] = ah[hd * 128 + wn + nb * 16 + lr];
    aD[nb] = ah[hd * 128 + 64 + wn + nb * 16 + lr];
  }
#pragma unroll
  for (int mb = 0; mb < 4; ++mb)
#pragma unroll
    for (int reg = 0; reg < 4; ++reg) {
      float ps = acc[mb][0][reg] * aS[0] + acc[mb][1][reg] * aS[1];
      float pd = acc[mb][0][reg] * aD[0] + acc[mb][1][reg] * aD[1];
#pragma unroll
      for (int m = 1; m < 16; m <<= 1) { ps += __shfl_xor(ps, m); pd += __shfl_xor(pd, m); }
      if (lr == 0) {
        int rl = wm + mb * 16 + kg * 4 + reg;
        sredS[rl][w >> 1] = ps;
        sredD[rl][w >> 1] = pd;
      }
    }
  __syncthreads();
  if (t < 128) {
    float vs = sredS[t][0] + sredS[t][1];
    float vd = sredD[t][0] + sredD[t][1];
    ssrc[(size_t)hd * N + i0 + t] = vs;
    sdst[(size_t)hd * N + i0 + t] = vd;
    float m = vd;
#pragma unroll
    for (int mk = 32; mk; mk >>= 1) m = fmaxf(m, __shfl_xor(m, mk));
    if ((t & 63) == 0) atomicMax(tmax1u + hd, mono(m));
  }
}

// ---------------------------------------------------------------------------
// K2a: layer-1 direct attention PARTIALS via MFMA, j-split.
// B tile staged K-MAJOR: hsTk[ku][row] (ku stride 257 dwords, odd) ->
// read bank-start = (kg + 4*lr) mod 32: 2 lanes/bank = free; staging
// writes (cu + 4r) mod 32: conflict-free. E-pack = truncation (proven).
// grid (N/64, NHEADS*JSPL1) x 256 thr.
// ---------------------------------------------------------------------------
__global__ __launch_bounds__(256) void k_attn1(const float* __restrict__ ssrc,
                                               const float* __restrict__ sdst,
                                               const unsigned short* __restrict__ h1T,
                                               const unsigned* __restrict__ tmax1u,
                                               float* __restrict__ pnum1,
                                               float* __restrict__ pz1) {
  __shared__ float tl[J1];                 // 1 KB
  __shared__ unsigned hsTk[32 * KUSTR];    // ~32.1 KB, k-major
  const int hd = blockIdx.y >> 1;
  const int jb = blockIdx.y & 1;
  const int tid = threadIdx.x, w = tid >> 6, lane = tid & 63;
  const int lr = lane & 15, kg = lane >> 4;
  const int row16 = blockIdx.x * 64 + w * 16;
  const unsigned short* hTh = h1T + (size_t)hd * NHID * N;
  const float* th = sdst + (size_t)hd * N;
  float tmax = unmono(tmax1u[hd]);
  float s = ssrc[(size_t)hd * N + row16 + lr];
  float v0 = s + tmax;
  float rowm = fmaxf(v0, ALPHA * v0);  // exact row max (monotone LeakyReLU)
  f32x4 acc[4];
#pragma unroll
  for (int nb = 0; nb < 4; ++nb) acc[nb] = (f32x4){0.f, 0.f, 0.f, 0.f};
  float zpart = 0.f;

  const int jc0 = jb * (N / J1 / JSPL1);
  for (int jc = jc0; jc < jc0 + N / J1 / JSPL1; ++jc) {
    if (tid < 64) *(float4*)(tl + tid * 4) = *(const float4*)(th + jc * J1 + tid * 4);
    // stage 64 rows x 32 k-units, k-major: unit (cu,row) at cu*KUSTR + r*4 dw
#pragma unroll
    for (int rep = 0; rep < 8; ++rep) {
      int u = rep * 256 + tid;
      int r = u >> 5, cu = u & 31;
      *(uint4*)(hsTk + cu * KUSTR + r * 4) =
          *(const uint4*)(hTh + (size_t)r * N + jc * J1 + cu * 8);
    }
    __syncthreads();
#pragma unroll
    for (int c = 0; c < J1 / 32; ++c) {
      const float* tp = tl + c * 32 + kg * 8;
      float e[8];
#pragma unroll
      for (int m = 0; m < 8; ++m) {
        float v = s + tp[m];
        e[m] = __expf(fmaxf(v, ALPHA * v) - rowm);
        zpart += e[m];
      }
      unsigned pk[4];
#pragma unroll
      for (int p = 0; p < 4; ++p)
        pk[p] = (__float_as_uint(e[2 * p + 1]) & 0xFFFF0000u) |
                (__float_as_uint(e[2 * p]) >> 16);
      bf16x8 af = __builtin_bit_cast(bf16x8, *(uint4*)pk);
      const int kub = (c * 4 + kg) * KUSTR;
#pragma unroll
      for (int nb = 0; nb < 4; ++nb) {
        bf16x8 bf = __builtin_bit_cast(bf16x8,
            *(const uint4*)(hsTk + kub + (nb * 16 + lr) * 4));
        acc[nb] = __builtin_amdgcn_mfma_f32_16x16x32_bf16(af, bf, acc[nb], 0, 0, 0);
      }
    }
    __syncthreads();
  }
  // Z per row r lives in lanes {r, r+16, r+32, r+48}
  zpart += __shfl_xor(zpart, 16);
  zpart += __shfl_xor(zpart, 32);
  float* pn = pnum1 + ((size_t)(jb * NHEADS + hd) * N) * NHID;
#pragma unroll
  for (int reg = 0; reg < 4; ++reg) {
    int row = row16 + kg * 4 + reg;
#pragma unroll
    for (int nb = 0; nb < 4; ++nb)
      pn[(size_t)row * NHID + nb * 16 + lr] = acc[nb][reg];
  }
  if (lane < 16)
    pz1[(size_t)(jb * NHEADS + hd) * N + row16 + lane] = zpart;
}

// ---------------------------------------------------------------------------
// K2b: layer-1 combine partials + normalize + ELU -> xcb (bf16, head-major).
// grid (N/4, NHEADS) x 256 thr; wave = 1 row, lane = d.
// ---------------------------------------------------------------------------
__global__ __launch_bounds__(256) void k_attn1f(const float* __restrict__ pnum1,
                                                const float* __restrict__ pz1,
                                                unsigned short* __restrict__ xcb) {
  int hd = blockIdx.y;
  int w = threadIdx.x >> 6, lane = threadIdx.x & 63;
  int row = blockIdx.x * 4 + w;
  float nsum = 0.f, zsum = 0.f;
#pragma unroll
  for (int jb = 0; jb < JSPL1; ++jb) {
    nsum += pnum1[((size_t)(jb * NHEADS + hd) * N + row) * NHID + lane];
    zsum += pz1[(size_t)(jb * NHEADS + hd) * N + row];
  }
  float f = nsum / zsum;
  float e = f > 0.f ? f : expf(f) - 1.f;  // ELU
  xcb[(size_t)row * (NHEADS * NHID) + hd * NHID + lane] = f2bf(e);
}

// ---------------------------------------------------------------------------
// K3: h2 = xc @ Wo via MFMA + fused layer-2 scores + deterministic global
// tmax. h2 stored bf16.
// ---------------------------------------------------------------------------
__global__ __launch_bounds__(256) void k_gemm2(const unsigned short* __restrict__ xcb,
                                               const unsigned short* __restrict__ Wt2,
                                               const float* __restrict__ ao,
                                               unsigned short* __restrict__ h2b,
                                               float* __restrict__ ssrc,
                                               float* __restrict__ sdst,
                                               unsigned* __restrict__ tmax2u) {
  const int t = threadIdx.x;
  const int w = t >> 6, lane = t & 63;
  const int lr = lane & 15, kg = lane >> 4;
  const int i0 = blockIdx.x * 64 + w * 16;
  __shared__ float sd[64];
  f32x4 acc = (f32x4){0.f, 0.f, 0.f, 0.f};
  const unsigned short* arow = xcb + (size_t)(i0 + lr) * NFEAT;
  const unsigned short* brow = Wt2 + (size_t)lr * NFEAT;
#pragma unroll
  for (int k0 = 0; k0 < NFEAT; k0 += 32) {
    bf16x8 af = __builtin_bit_cast(bf16x8, *(const uint4*)(arow + k0 + kg * 8));
    bf16x8 bv = __builtin_bit_cast(bf16x8, *(const uint4*)(brow + k0 + kg * 8));
    acc = __builtin_amdgcn_mfma_f32_16x16x32_bf16(af, bv, acc, 0, 0, 0);
  }
  float aS = ao[lr], aD = ao[16 + lr];
#pragma unroll
  for (int reg = 0; reg < 4; ++reg) {
    int row = i0 + kg * 4 + reg;
    h2b[(size_t)row * NCLASS + lr] = f2bf(acc[reg]);
    float ps = acc[reg] * aS, pd = acc[reg] * aD;
#pragma unroll
    for (int m = 1; m < 16; m <<= 1) { ps += __shfl_xor(ps, m); pd += __shfl_xor(pd, m); }
    if (lr == 0) {
      ssrc[row] = ps;
      sdst[row] = pd;
      sd[w * 16 + kg * 4 + reg] = pd;
    }
  }
  __syncthreads();
  if (t < 64) {
    float v = sd[t];
#pragma unroll
    for (int m = 32; m; m >>= 1) v = fmaxf(v, __shfl_xor(v, m));
    if (t == 0) atomicMax(tmax2u, mono(v));
  }
}

// ---------------------------------------------------------------------------
// K4a: layer-2 attention partials via MFMA (unchanged, proven).
// ---------------------------------------------------------------------------
__global__ __launch_bounds__(256) void k_attn2p(const float* __restrict__ ssrc,
                                                const float* __restrict__ t,
                                                const unsigned short* __restrict__ h2b,
                                                const unsigned* __restrict__ tmax2u,
                                                float* __restrict__ pnum,
                                                float* __restrict__ pz) {
  __shared__ float tl[JLEN];                    // 2 KB
  __shared__ unsigned short hsT[16 * HSTR];     // 16.25 KB, transposed h2
  int tid = threadIdx.x;
  int jb = blockIdx.y;
  if (tid < 128) {
    int i4 = tid * 4;
    *(float4*)(tl + i4) = *(const float4*)(t + jb * JLEN + i4);
  }
#pragma unroll
  for (int rep = 0; rep < 2; ++rep) {
    int j = rep * 256 + tid;
    const uint4* src = (const uint4*)(h2b + (size_t)(jb * JLEN + j) * NCLASS);
    uint4 a = src[0], b = src[1];
    unsigned short v[16];
    *(uint4*)v = a; *(uint4*)(v + 8) = b;
#pragma unroll
    for (int c = 0; c < 16; ++c) hsT[c * HSTR + j] = v[c];
  }
  __syncthreads();
  int w = tid >> 6, lane = tid & 63;
  int lr = lane & 15, kg = lane >> 4;
  int ib = blockIdx.x * 64 + w * 16;
  float tmax = unmono(*tmax2u);
  float s = ssrc[ib + lr];
  float v0 = s + tmax;
  float rowm = fmaxf(v0, ALPHA * v0);
  f32x4 acc = (f32x4){0.f, 0.f, 0.f, 0.f};
  float zpart = 0.f;
#pragma unroll
  for (int c = 0; c < JLEN / 32; ++c) {
    const float* tp = tl + c * 32 + kg * 8;
    float e[8];
#pragma unroll
    for (int m = 0; m < 8; ++m) {
      float v = s + tp[m];
      e[m] = __expf(fmaxf(v, ALPHA * v) - rowm);
      zpart += e[m];
    }
    unsigned pk[4];
#pragma unroll
    for (int p = 0; p < 4; ++p)
      pk[p] = ((unsigned)f2bf(e[2 * p + 1]) << 16) | (unsigned)f2bf(e[2 * p]);
    bf16x8 af = __builtin_bit_cast(bf16x8, *(uint4*)pk);
    bf16x8 bf = __builtin_bit_cast(bf16x8,
        *(const uint4*)(hsT + lr * HSTR + c * 32 + kg * 8));
    acc = __builtin_amdgcn_mfma_f32_16x16x32_bf16(af, bf, acc, 0, 0, 0);
  }
  zpart += __shfl_xor(zpart, 16);
  zpart += __shfl_xor(zpart, 32);
#pragma unroll
  for (int reg = 0; reg < 4; ++reg)
    pnum[((size_t)jb * N + ib + kg * 4 + reg) * NCLASS + lr] = acc[reg];
  if (lane < 16) pz[(size_t)jb * N + ib + lane] = zpart;
}

// ---------------------------------------------------------------------------
// K4b: combine partials + ELU + log_softmax.
// ---------------------------------------------------------------------------
__global__ __launch_bounds__(256) void k_attn2f(const float* __restrict__ pnum,
                                                const float* __restrict__ pz,
                                                float* __restrict__ out) {
  int g = threadIdx.x >> 4, cl = threadIdx.x & 15;
  int i = blockIdx.x * 16 + g;
  float nsum = 0.f, zsum = 0.f;
#pragma unroll
  for (int jb = 0; jb < JSPL; ++jb) {
    nsum += pnum[((size_t)jb * N + i) * NCLASS + cl];
    zsum += pz[(size_t)jb * N + i];
  }
  float o = nsum / zsum;
  o = o > 0.f ? o : expf(o) - 1.f;  // ELU
  float mo = o;
#pragma unroll
  for (int mk = 1; mk < 16; mk <<= 1) mo = fmaxf(mo, __shfl_xor(mo, mk, 16));
  float sum = expf(o - mo);
#pragma unroll
  for (int mk = 1; mk < 16; mk <<= 1) sum += __shfl_xor(sum, mk, 16);
  out[(size_t)i * NCLASS + cl] = o - mo - logf(sum);
}

// ---------------------------------------------------------------------------
extern "C" void kernel_launch(void* const* d_in, const int* in_sizes, int n_in,
                              void* d_out, int out_size, void* d_ws, size_t ws_size,
                              hipStream_t stream) {
  const float* x  = (const float*)d_in[0];
  const float* Wh = (const float*)d_in[1];
  const float* ah = (const float*)d_in[2];
  const float* Wo = (const float*)d_in[3];
  const float* ao = (const float*)d_in[4];
  float* out = (float*)d_out;

  char* base = (char*)d_ws;
  size_t off = 0;
  auto alloc_f = [&](size_t n) -> float* {
    float* p = (float*)(base + off);
    off = (off + n * sizeof(float) + 255) & ~(size_t)255;
    return p;
  };
  auto alloc_i = [&](size_t n) -> int* {
    int* p = (int*)(base + off);
    off = (off + n * sizeof(int) + 255) & ~(size_t)255;
    return p;
  };
  auto alloc_u16 = [&](size_t n) -> unsigned short* {
    unsigned short* p = (unsigned short*)(base + off);
    off = (off + n * sizeof(unsigned short) + 255) & ~(size_t)255;
    return p;
  };

  unsigned short* xbf = alloc_u16((size_t)N * NFEAT);
  unsigned short* Wt  = alloc_u16((size_t)NHEADS * NHID * NFEAT);
  unsigned short* Wt2 = alloc_u16((size_t)NCLASS * NFEAT);
  unsigned short* h1T = alloc_u16((size_t)NHEADS * NHID * N);
  float* ssrc1 = alloc_f((size_t)NHEADS * N);
  float* sdst1 = alloc_f((size_t)NHEADS * N);
  unsigned* tmax1u = (unsigned*)alloc_i(NHEADS);
  float* pnum1 = alloc_f((size_t)JSPL1 * NHEADS * N * NHID);
  float* pz1   = alloc_f((size_t)JSPL1 * NHEADS * N);
  unsigned short* xcb = alloc_u16((size_t)N * NHEADS * NHID);
  unsigned short* h2b = alloc_u16((size_t)N * NCLASS);
  float* ssrc2 = alloc_f(N);
  float* sdst2 = alloc_f(N);
  unsigned* tmax2u = (unsigned*)alloc_i(1);
  float* pnum  = alloc_f((size_t)JSPL * N * NCLASS);
  float* pz    = alloc_f((size_t)JSPL * N);

  if (off > ws_size) return;

  hipLaunchKernelGGL(k_pack, dim3(2113), dim3(256), 0, stream, x, Wh, Wo, xbf, Wt, Wt2, tmax1u, tmax2u);

  // ---- Layer 1 (MFMA direct attention, j-split) ----
  hipLaunchKernelGGL(k_gemm_h, dim3(N / 128, NHEADS), dim3(256), 0, stream, xbf, Wt, ah, h1T, ssrc1, sdst1, tmax1u);
  hipLaunchKernelGGL(k_attn1, dim3(N / 64, NHEADS * JSPL1), dim3(256), 0, stream, ssrc1, sdst1, h1T, tmax1u, pnum1, pz1);
  hipLaunchKernelGGL(k_attn1f, dim3(N / 4, NHEADS), dim3(256), 0, stream, pnum1, pz1, xcb);

  // ---- Layer 2 (MFMA direct attention) ----
  hipLaunchKernelGGL(k_gemm2, dim3(N / 64), dim3(256), 0, stream, xcb, Wt2, ao, h2b, ssrc2, sdst2, tmax2u);
  hipLaunchKernelGGL(k_attn2p, dim3(N / 64, JSPL), dim3(256), 0, stream, ssrc2, sdst2, h2b, tmax2u, pnum, pz);
  hipLaunchKernelGGL(k_attn2f, dim3(N / 16), dim3(256), 0, stream, pnum, pz, out);
}

// Round 23
// 109.624 us; speedup vs baseline: 1.0188x; 1.0188x over previous
//
#include <hip/hip_runtime.h>
#include <math.h>

#define N 4096
#define NFEAT 512
#define NHID 64
#define NCLASS 16
#define NHEADS 8
#define ALPHA 0.2f
#define JSPL 8            // layer-2 j-split
#define JLEN (N / JSPL)   // 512
#define HSTR 520          // layer-2 hsT row stride (ushorts)
#define J1 128            // layer-1 j sub-chunk (small -> 8 blocks/CU)
#define H1STR 136         // layer-1 hsT row stride (ushorts)
#define JSPL1 2           // layer-1 j-split

typedef __attribute__((ext_vector_type(8))) short bf16x8;
typedef __attribute__((ext_vector_type(4))) float f32x4;

__device__ inline unsigned short f2bf(float f) {
  unsigned u = __float_as_uint(f);
  unsigned r = u + 0x7fffu + ((u >> 16) & 1u);  // RNE
  return (unsigned short)(r >> 16);
}
__device__ inline unsigned mono(float f) {
  unsigned u = __float_as_uint(f);
  return (u & 0x80000000u) ? ~u : (u | 0x80000000u);
}
__device__ inline float unmono(unsigned m) {
  return (m >> 31) ? __uint_as_float(m & 0x7FFFFFFFu) : __uint_as_float(~m);
}

// ---------------------------------------------------------------------------
// P0: pack. blocks [0,2048): x->bf16; [2048,2112): Wt=bf16(Wh^T);
// 2112: Wt2 + tmax inits.
// ---------------------------------------------------------------------------
__global__ __launch_bounds__(256) void k_pack(const float* __restrict__ x,
                                              const float* __restrict__ Wh,
                                              const float* __restrict__ Wo,
                                              unsigned short* __restrict__ xb,
                                              unsigned short* __restrict__ Wt,
                                              unsigned short* __restrict__ Wt2,
                                              unsigned* __restrict__ tmax1u,
                                              unsigned* __restrict__ tmax2u) {
  int b = blockIdx.x;
  if (b < 2048) {
    int i = (b * 256 + threadIdx.x) * 4;
    float4 v = *(const float4*)(x + i);
    ushort4 o;
    o.x = f2bf(v.x); o.y = f2bf(v.y); o.z = f2bf(v.z); o.w = f2bf(v.w);
    *(ushort4*)(xb + i) = o;
  } else if (b < 2112) {
    int idx = b - 2048;
    int kt = idx & 7, hd = idx >> 3;
    __shared__ float ld[64][65];
    const float* src = Wh + ((size_t)hd * NFEAT + kt * 64) * NHID;
    int r = threadIdx.x >> 2, c0 = (threadIdx.x & 3) * 16;
#pragma unroll
    for (int j = 0; j < 4; ++j) {
      float4 v = *(const float4*)(src + (size_t)r * NHID + c0 + j * 4);
      ld[r][c0 + j * 4 + 0] = v.x; ld[r][c0 + j * 4 + 1] = v.y;
      ld[r][c0 + j * 4 + 2] = v.z; ld[r][c0 + j * 4 + 3] = v.w;
    }
    __syncthreads();
    int n = threadIdx.x >> 2, kq = threadIdx.x & 3;
    unsigned short tmp[16];
#pragma unroll
    for (int j = 0; j < 16; ++j) tmp[j] = f2bf(ld[kq * 16 + j][n]);
    unsigned short* dst = Wt + ((size_t)hd * 64 + n) * NFEAT + kt * 64 + kq * 16;
    ((uint4*)dst)[0] = *(uint4*)tmp;
    ((uint4*)dst)[1] = *(uint4*)(tmp + 8);
  } else {
    for (int e = threadIdx.x; e < NFEAT * NCLASS; e += 256) {
      int n = e & 15, k = e >> 4;
      Wt2[(size_t)n * NFEAT + k] = f2bf(Wo[(size_t)k * NCLASS + n]);
    }
    if (threadIdx.x < NHEADS) tmax1u[threadIdx.x] = 0u;  // mono(-inf)
    if (threadIdx.x == 0) *tmax2u = 0u;
  }
}

// ---------------------------------------------------------------------------
// K1: MFMA bf16 GEMM h = x @ Wh per head, 128x64 tile, 4 waves, fused scores
// + per-head tmax. h written TRANSPOSED: h1T[hd][d][j] (bf16).
// ---------------------------------------------------------------------------
__global__ __launch_bounds__(256) void k_gemm_h(const unsigned short* __restrict__ xb,
                                                const unsigned short* __restrict__ Wt,
                                                const float* __restrict__ ah,
                                                unsigned short* __restrict__ h1T,
                                                float* __restrict__ ssrc,
                                                float* __restrict__ sdst,
                                                unsigned* __restrict__ tmax1u) {
  const int hd = blockIdx.y;
  const int i0 = blockIdx.x * 128;
  const int t = threadIdx.x;
  const int w = t >> 6, lane = t & 63;
  const int lr = lane & 15, kg = lane >> 4;
  const int wm = (w & 1) * 64, wn = (w >> 1) * 32;
  __shared__ uint4 Als[128][4];
  __shared__ uint4 Bls[64][4];
  __shared__ float sredS[128][2];
  __shared__ float sredD[128][2];
  const unsigned short* xrow = xb + (size_t)i0 * NFEAT;
  const unsigned short* wrow = Wt + (size_t)hd * 64 * NFEAT;

  f32x4 acc[4][2];
#pragma unroll
  for (int a = 0; a < 4; ++a)
#pragma unroll
    for (int b = 0; b < 2; ++b) acc[a][b] = (f32x4){0.f, 0.f, 0.f, 0.f};

  const int u0 = t, u1 = t + 256;
  const int ra0 = u0 >> 2, sa0 = ((u0 & 3) ^ (ra0 & 3)) * 8;
  const int ra1 = u1 >> 2, sa1 = ((u1 & 3) ^ (ra1 & 3)) * 8;
  const int rb0 = t >> 2,  sb0 = ((t & 3) ^ (rb0 & 3)) * 8;
  const int wbase = t & ~63;

  for (int k0 = 0; k0 < NFEAT; k0 += 32) {
    __builtin_amdgcn_global_load_lds(
        (const __attribute__((address_space(1))) void*)(xrow + (size_t)ra0 * NFEAT + k0 + sa0),
        (__attribute__((address_space(3))) void*)((uint4*)Als + wbase), 16, 0, 0);
    __builtin_amdgcn_global_load_lds(
        (const __attribute__((address_space(1))) void*)(xrow + (size_t)ra1 * NFEAT + k0 + sa1),
        (__attribute__((address_space(3))) void*)((uint4*)Als + 256 + wbase), 16, 0, 0);
    __builtin_amdgcn_global_load_lds(
        (const __attribute__((address_space(1))) void*)(wrow + (size_t)rb0 * NFEAT + k0 + sb0),
        (__attribute__((address_space(3))) void*)((uint4*)Bls + wbase), 16, 0, 0);
    __syncthreads();
    bf16x8 af[4], bfv[2];
#pragma unroll
    for (int mb = 0; mb < 4; ++mb) {
      int row = wm + mb * 16 + lr;
      af[mb] = __builtin_bit_cast(bf16x8, Als[row][kg ^ (row & 3)]);
    }
#pragma unroll
    for (int nb = 0; nb < 2; ++nb) {
      int col = wn + nb * 16 + lr;
      bfv[nb] = __builtin_bit_cast(bf16x8, Bls[col][kg ^ (col & 3)]);
    }
#pragma unroll
    for (int mb = 0; mb < 4; ++mb)
#pragma unroll
      for (int nb = 0; nb < 2; ++nb)
        acc[mb][nb] = __builtin_amdgcn_mfma_f32_16x16x32_bf16(af[mb], bfv[nb], acc[mb][nb], 0, 0, 0);
    __syncthreads();
  }

  unsigned short* hT = h1T + (size_t)hd * NHID * N;
#pragma unroll
  for (int mb = 0; mb < 4; ++mb)
#pragma unroll
    for (int nb = 0; nb < 2; ++nb) {
      int col = wn + nb * 16 + lr;
      int rbase = i0 + wm + mb * 16 + kg * 4;
      ushort4 o;
      o.x = f2bf(acc[mb][nb][0]); o.y = f2bf(acc[mb][nb][1]);
      o.z = f2bf(acc[mb][nb][2]); o.w = f2bf(acc[mb][nb][3]);
      *(ushort4*)(hT + (size_t)col * N + rbase) = o;
    }

  float aS[2], aD[2];
#pragma unroll
  for (int nb = 0; nb < 2; ++nb) {
    aS[nb] = ah[hd * 128 + wn + nb * 16 + lr];
    aD[nb] = ah[hd * 128 + 64 + wn + nb * 16 + lr];
  }
#pragma unroll
  for (int mb = 0; mb < 4; ++mb)
#pragma unroll
    for (int reg = 0; reg < 4; ++reg) {
      float ps = acc[mb][0][reg] * aS[0] + acc[mb][1][reg] * aS[1];
      float pd = acc[mb][0][reg] * aD[0] + acc[mb][1][reg] * aD[1];
#pragma unroll
      for (int m = 1; m < 16; m <<= 1) { ps += __shfl_xor(ps, m); pd += __shfl_xor(pd, m); }
      if (lr == 0) {
        int rl = wm + mb * 16 + kg * 4 + reg;
        sredS[rl][w >> 1] = ps;
        sredD[rl][w >> 1] = pd;
      }
    }
  __syncthreads();
  if (t < 128) {
    float vs = sredS[t][0] + sredS[t][1];
    float vd = sredD[t][0] + sredD[t][1];
    ssrc[(size_t)hd * N + i0 + t] = vs;
    sdst[(size_t)hd * N + i0 + t] = vd;
    float m = vd;
#pragma unroll
    for (int mk = 32; mk; mk >>= 1) m = fmaxf(m, __shfl_xor(m, mk));
    if ((t & 63) == 0) atomicMax(tmax1u + hd, mono(m));
  }
}

// ---------------------------------------------------------------------------
// K2a: layer-1 direct attention PARTIALS via MFMA, j-split (r21 structure,
// J1=128 for 8 blocks/CU occupancy). E-pack = truncation (proven r18/r21).
// grid (N/64, NHEADS*JSPL1) x 256 thr.
// ---------------------------------------------------------------------------
__global__ __launch_bounds__(256) void k_attn1(const float* __restrict__ ssrc,
                                               const float* __restrict__ sdst,
                                               const unsigned short* __restrict__ h1T,
                                               const unsigned* __restrict__ tmax1u,
                                               float* __restrict__ pnum1,
                                               float* __restrict__ pz1) {
  __shared__ float tl[J1];                     // 0.5 KB
  __shared__ unsigned short hsT[64 * H1STR];   // 17.4 KB
  const int hd = blockIdx.y >> 1;
  const int jb = blockIdx.y & 1;
  const int tid = threadIdx.x, w = tid >> 6, lane = tid & 63;
  const int lr = lane & 15, kg = lane >> 4;
  const int row16 = blockIdx.x * 64 + w * 16;
  const unsigned short* hTh = h1T + (size_t)hd * NHID * N;
  const float* th = sdst + (size_t)hd * N;
  float tmax = unmono(tmax1u[hd]);
  float s = ssrc[(size_t)hd * N + row16 + lr];
  float v0 = s + tmax;
  float rowm = fmaxf(v0, ALPHA * v0);  // exact row max (monotone LeakyReLU)
  f32x4 acc[4];
#pragma unroll
  for (int nb = 0; nb < 4; ++nb) acc[nb] = (f32x4){0.f, 0.f, 0.f, 0.f};
  float zpart = 0.f;

  const int jc0 = jb * (N / J1 / JSPL1);
  for (int jc = jc0; jc < jc0 + N / J1 / JSPL1; ++jc) {
    if (tid < 32) *(float4*)(tl + tid * 4) = *(const float4*)(th + jc * J1 + tid * 4);
    // stage 64 rows x 128 bf16 (16 units of 8 per row)
#pragma unroll
    for (int rep = 0; rep < 4; ++rep) {
      int u = rep * 256 + tid;
      int r = u >> 4, cu = u & 15;
      *(uint4*)(hsT + r * H1STR + cu * 8) =
          *(const uint4*)(hTh + (size_t)r * N + jc * J1 + cu * 8);
    }
    __syncthreads();
#pragma unroll
    for (int c = 0; c < J1 / 32; ++c) {
      const float* tp = tl + c * 32 + kg * 8;
      float e[8];
#pragma unroll
      for (int m = 0; m < 8; ++m) {
        float v = s + tp[m];
        e[m] = __expf(fmaxf(v, ALPHA * v) - rowm);
        zpart += e[m];
      }
      unsigned pk[4];
#pragma unroll
      for (int p = 0; p < 4; ++p)
        pk[p] = (__float_as_uint(e[2 * p + 1]) & 0xFFFF0000u) |
                (__float_as_uint(e[2 * p]) >> 16);
      bf16x8 af = __builtin_bit_cast(bf16x8, *(uint4*)pk);
#pragma unroll
      for (int nb = 0; nb < 4; ++nb) {
        bf16x8 bf = __builtin_bit_cast(bf16x8,
            *(const uint4*)(hsT + (nb * 16 + lr) * H1STR + c * 32 + kg * 8));
        acc[nb] = __builtin_amdgcn_mfma_f32_16x16x32_bf16(af, bf, acc[nb], 0, 0, 0);
      }
    }
    __syncthreads();
  }
  // Z per row r lives in lanes {r, r+16, r+32, r+48}
  zpart += __shfl_xor(zpart, 16);
  zpart += __shfl_xor(zpart, 32);
  float* pn = pnum1 + ((size_t)(jb * NHEADS + hd) * N) * NHID;
#pragma unroll
  for (int reg = 0; reg < 4; ++reg) {
    int row = row16 + kg * 4 + reg;
#pragma unroll
    for (int nb = 0; nb < 4; ++nb)
      pn[(size_t)row * NHID + nb * 16 + lr] = acc[nb][reg];
  }
  if (lane < 16)
    pz1[(size_t)(jb * NHEADS + hd) * N + row16 + lane] = zpart;
}

// ---------------------------------------------------------------------------
// K2b: layer-1 combine partials + normalize + ELU -> xcb (bf16, head-major).
// grid (N/4, NHEADS) x 256 thr; wave = 1 row, lane = d.
// ---------------------------------------------------------------------------
__global__ __launch_bounds__(256) void k_attn1f(const float* __restrict__ pnum1,
                                                const float* __restrict__ pz1,
                                                unsigned short* __restrict__ xcb) {
  int hd = blockIdx.y;
  int w = threadIdx.x >> 6, lane = threadIdx.x & 63;
  int row = blockIdx.x * 4 + w;
  float nsum = 0.f, zsum = 0.f;
#pragma unroll
  for (int jb = 0; jb < JSPL1; ++jb) {
    nsum += pnum1[((size_t)(jb * NHEADS + hd) * N + row) * NHID + lane];
    zsum += pz1[(size_t)(jb * NHEADS + hd) * N + row];
  }
  float f = nsum / zsum;
  float e = f > 0.f ? f : expf(f) - 1.f;  // ELU
  xcb[(size_t)row * (NHEADS * NHID) + hd * NHID + lane] = f2bf(e);
}

// ---------------------------------------------------------------------------
// K3: h2 = xc @ Wo via MFMA + fused layer-2 scores + deterministic global
// tmax. h2 stored bf16.
// ---------------------------------------------------------------------------
__global__ __launch_bounds__(256) void k_gemm2(const unsigned short* __restrict__ xcb,
                                               const unsigned short* __restrict__ Wt2,
                                               const float* __restrict__ ao,
                                               unsigned short* __restrict__ h2b,
                                               float* __restrict__ ssrc,
                                               float* __restrict__ sdst,
                                               unsigned* __restrict__ tmax2u) {
  const int t = threadIdx.x;
  const int w = t >> 6, lane = t & 63;
  const int lr = lane & 15, kg = lane >> 4;
  const int i0 = blockIdx.x * 64 + w * 16;
  __shared__ float sd[64];
  f32x4 acc = (f32x4){0.f, 0.f, 0.f, 0.f};
  const unsigned short* arow = xcb + (size_t)(i0 + lr) * NFEAT;
  const unsigned short* brow = Wt2 + (size_t)lr * NFEAT;
#pragma unroll
  for (int k0 = 0; k0 < NFEAT; k0 += 32) {
    bf16x8 af = __builtin_bit_cast(bf16x8, *(const uint4*)(arow + k0 + kg * 8));
    bf16x8 bv = __builtin_bit_cast(bf16x8, *(const uint4*)(brow + k0 + kg * 8));
    acc = __builtin_amdgcn_mfma_f32_16x16x32_bf16(af, bv, acc, 0, 0, 0);
  }
  float aS = ao[lr], aD = ao[16 + lr];
#pragma unroll
  for (int reg = 0; reg < 4; ++reg) {
    int row = i0 + kg * 4 + reg;
    h2b[(size_t)row * NCLASS + lr] = f2bf(acc[reg]);
    float ps = acc[reg] * aS, pd = acc[reg] * aD;
#pragma unroll
    for (int m = 1; m < 16; m <<= 1) { ps += __shfl_xor(ps, m); pd += __shfl_xor(pd, m); }
    if (lr == 0) {
      ssrc[row] = ps;
      sdst[row] = pd;
      sd[w * 16 + kg * 4 + reg] = pd;
    }
  }
  __syncthreads();
  if (t < 64) {
    float v = sd[t];
#pragma unroll
    for (int m = 32; m; m >>= 1) v = fmaxf(v, __shfl_xor(v, m));
    if (t == 0) atomicMax(tmax2u, mono(v));
  }
}

// ---------------------------------------------------------------------------
// K4a: layer-2 attention partials via MFMA (unchanged, proven).
// ---------------------------------------------------------------------------
__global__ __launch_bounds__(256) void k_attn2p(const float* __restrict__ ssrc,
                                                const float* __restrict__ t,
                                                const unsigned short* __restrict__ h2b,
                                                const unsigned* __restrict__ tmax2u,
                                                float* __restrict__ pnum,
                                                float* __restrict__ pz) {
  __shared__ float tl[JLEN];                    // 2 KB
  __shared__ unsigned short hsT[16 * HSTR];     // 16.25 KB, transposed h2
  int tid = threadIdx.x;
  int jb = blockIdx.y;
  if (tid < 128) {
    int i4 = tid * 4;
    *(float4*)(tl + i4) = *(const float4*)(t + jb * JLEN + i4);
  }
#pragma unroll
  for (int rep = 0; rep < 2; ++rep) {
    int j = rep * 256 + tid;
    const uint4* src = (const uint4*)(h2b + (size_t)(jb * JLEN + j) * NCLASS);
    uint4 a = src[0], b = src[1];
    unsigned short v[16];
    *(uint4*)v = a; *(uint4*)(v + 8) = b;
#pragma unroll
    for (int c = 0; c < 16; ++c) hsT[c * HSTR + j] = v[c];
  }
  __syncthreads();
  int w = tid >> 6, lane = tid & 63;
  int lr = lane & 15, kg = lane >> 4;
  int ib = blockIdx.x * 64 + w * 16;
  float tmax = unmono(*tmax2u);
  float s = ssrc[ib + lr];
  float v0 = s + tmax;
  float rowm = fmaxf(v0, ALPHA * v0);
  f32x4 acc = (f32x4){0.f, 0.f, 0.f, 0.f};
  float zpart = 0.f;
#pragma unroll
  for (int c = 0; c < JLEN / 32; ++c) {
    const float* tp = tl + c * 32 + kg * 8;
    float e[8];
#pragma unroll
    for (int m = 0; m < 8; ++m) {
      float v = s + tp[m];
      e[m] = __expf(fmaxf(v, ALPHA * v) - rowm);
      zpart += e[m];
    }
    unsigned pk[4];
#pragma unroll
    for (int p = 0; p < 4; ++p)
      pk[p] = ((unsigned)f2bf(e[2 * p + 1]) << 16) | (unsigned)f2bf(e[2 * p]);
    bf16x8 af = __builtin_bit_cast(bf16x8, *(uint4*)pk);
    bf16x8 bf = __builtin_bit_cast(bf16x8,
        *(const uint4*)(hsT + lr * HSTR + c * 32 + kg * 8));
    acc = __builtin_amdgcn_mfma_f32_16x16x32_bf16(af, bf, acc, 0, 0, 0);
  }
  zpart += __shfl_xor(zpart, 16);
  zpart += __shfl_xor(zpart, 32);
#pragma unroll
  for (int reg = 0; reg < 4; ++reg)
    pnum[((size_t)jb * N + ib + kg * 4 + reg) * NCLASS + lr] = acc[reg];
  if (lane < 16) pz[(size_t)jb * N + ib + lane] = zpart;
}

// ---------------------------------------------------------------------------
// K4b: combine partials + ELU + log_softmax.
// ---------------------------------------------------------------------------
__global__ __launch_bounds__(256) void k_attn2f(const float* __restrict__ pnum,
                                                const float* __restrict__ pz,
                                                float* __restrict__ out) {
  int g = threadIdx.x >> 4, cl = threadIdx.x & 15;
  int i = blockIdx.x * 16 + g;
  float nsum = 0.f, zsum = 0.f;
#pragma unroll
  for (int jb = 0; jb < JSPL; ++jb) {
    nsum += pnum[((size_t)jb * N + i) * NCLASS + cl];
    zsum += pz[(size_t)jb * N + i];
  }
  float o = nsum / zsum;
  o = o > 0.f ? o : expf(o) - 1.f;  // ELU
  float mo = o;
#pragma unroll
  for (int mk = 1; mk < 16; mk <<= 1) mo = fmaxf(mo, __shfl_xor(mo, mk, 16));
  float sum = expf(o - mo);
#pragma unroll
  for (int mk = 1; mk < 16; mk <<= 1) sum += __shfl_xor(sum, mk, 16);
  out[(size_t)i * NCLASS + cl] = o - mo - logf(sum);
}

// ---------------------------------------------------------------------------
extern "C" void kernel_launch(void* const* d_in, const int* in_sizes, int n_in,
                              void* d_out, int out_size, void* d_ws, size_t ws_size,
                              hipStream_t stream) {
  const float* x  = (const float*)d_in[0];
  const float* Wh = (const float*)d_in[1];
  const float* ah = (const float*)d_in[2];
  const float* Wo = (const float*)d_in[3];
  const float* ao = (const float*)d_in[4];
  float* out = (float*)d_out;

  char* base = (char*)d_ws;
  size_t off = 0;
  auto alloc_f = [&](size_t n) -> float* {
    float* p = (float*)(base + off);
    off = (off + n * sizeof(float) + 255) & ~(size_t)255;
    return p;
  };
  auto alloc_i = [&](size_t n) -> int* {
    int* p = (int*)(base + off);
    off = (off + n * sizeof(int) + 255) & ~(size_t)255;
    return p;
  };
  auto alloc_u16 = [&](size_t n) -> unsigned short* {
    unsigned short* p = (unsigned short*)(base + off);
    off = (off + n * sizeof(unsigned short) + 255) & ~(size_t)255;
    return p;
  };

  unsigned short* xbf = alloc_u16((size_t)N * NFEAT);
  unsigned short* Wt  = alloc_u16((size_t)NHEADS * NHID * NFEAT);
  unsigned short* Wt2 = alloc_u16((size_t)NCLASS * NFEAT);
  unsigned short* h1T = alloc_u16((size_t)NHEADS * NHID * N);
  float* ssrc1 = alloc_f((size_t)NHEADS * N);
  float* sdst1 = alloc_f((size_t)NHEADS * N);
  unsigned* tmax1u = (unsigned*)alloc_i(NHEADS);
  float* pnum1 = alloc_f((size_t)JSPL1 * NHEADS * N * NHID);
  float* pz1   = alloc_f((size_t)JSPL1 * NHEADS * N);
  unsigned short* xcb = alloc_u16((size_t)N * NHEADS * NHID);
  unsigned short* h2b = alloc_u16((size_t)N * NCLASS);
  float* ssrc2 = alloc_f(N);
  float* sdst2 = alloc_f(N);
  unsigned* tmax2u = (unsigned*)alloc_i(1);
  float* pnum  = alloc_f((size_t)JSPL * N * NCLASS);
  float* pz    = alloc_f((size_t)JSPL * N);

  if (off > ws_size) return;

  hipLaunchKernelGGL(k_pack, dim3(2113), dim3(256), 0, stream, x, Wh, Wo, xbf, Wt, Wt2, tmax1u, tmax2u);

  // ---- Layer 1 (MFMA direct attention, j-split) ----
  hipLaunchKernelGGL(k_gemm_h, dim3(N / 128, NHEADS), dim3(256), 0, stream, xbf, Wt, ah, h1T, ssrc1, sdst1, tmax1u);
  hipLaunchKernelGGL(k_attn1, dim3(N / 64, NHEADS * JSPL1), dim3(256), 0, stream, ssrc1, sdst1, h1T, tmax1u, pnum1, pz1);
  hipLaunchKernelGGL(k_attn1f, dim3(N / 4, NHEADS), dim3(256), 0, stream, pnum1, pz1, xcb);

  // ---- Layer 2 (MFMA direct attention) ----
  hipLaunchKernelGGL(k_gemm2, dim3(N / 64), dim3(256), 0, stream, xcb, Wt2, ao, h2b, ssrc2, sdst2, tmax2u);
  hipLaunchKernelGGL(k_attn2p, dim3(N / 64, JSPL), dim3(256), 0, stream, ssrc2, sdst2, h2b, tmax2u, pnum, pz);
  hipLaunchKernelGGL(k_attn2f, dim3(N / 16), dim3(256), 0, stream, pnum, pz, out);
}

// Round 24
// 105.673 us; speedup vs baseline: 1.0569x; 1.0374x over previous
//
#include <hip/hip_runtime.h>
#include <math.h>

#define N 4096
#define NFEAT 512
#define NHID 64
#define NCLASS 16
#define NHEADS 8
#define ALPHA 0.2f
#define JSPL 8            // layer-2 j-split
#define JLEN (N / JSPL)   // 512
#define HSTR 520          // layer-2 hsT row stride (ushorts)
#define J1 128            // layer-1 j sub-chunk
#define H1STR 136         // layer-1 hsT row stride (ushorts)
#define JSPL1 4           // layer-1 j-split -> grid 2048 blocks = 8/CU

typedef __attribute__((ext_vector_type(8))) short bf16x8;
typedef __attribute__((ext_vector_type(4))) float f32x4;

__device__ inline unsigned short f2bf(float f) {
  unsigned u = __float_as_uint(f);
  unsigned r = u + 0x7fffu + ((u >> 16) & 1u);  // RNE
  return (unsigned short)(r >> 16);
}
__device__ inline unsigned mono(float f) {
  unsigned u = __float_as_uint(f);
  return (u & 0x80000000u) ? ~u : (u | 0x80000000u);
}
__device__ inline float unmono(unsigned m) {
  return (m >> 31) ? __uint_as_float(m & 0x7FFFFFFFu) : __uint_as_float(~m);
}

// ---------------------------------------------------------------------------
// P0: pack. blocks [0,2048): x->bf16; [2048,2112): Wt=bf16(Wh^T);
// 2112: Wt2 + tmax inits.
// ---------------------------------------------------------------------------
__global__ __launch_bounds__(256) void k_pack(const float* __restrict__ x,
                                              const float* __restrict__ Wh,
                                              const float* __restrict__ Wo,
                                              unsigned short* __restrict__ xb,
                                              unsigned short* __restrict__ Wt,
                                              unsigned short* __restrict__ Wt2,
                                              unsigned* __restrict__ tmax1u,
                                              unsigned* __restrict__ tmax2u) {
  int b = blockIdx.x;
  if (b < 2048) {
    int i = (b * 256 + threadIdx.x) * 4;
    float4 v = *(const float4*)(x + i);
    ushort4 o;
    o.x = f2bf(v.x); o.y = f2bf(v.y); o.z = f2bf(v.z); o.w = f2bf(v.w);
    *(ushort4*)(xb + i) = o;
  } else if (b < 2112) {
    int idx = b - 2048;
    int kt = idx & 7, hd = idx >> 3;
    __shared__ float ld[64][65];
    const float* src = Wh + ((size_t)hd * NFEAT + kt * 64) * NHID;
    int r = threadIdx.x >> 2, c0 = (threadIdx.x & 3) * 16;
#pragma unroll
    for (int j = 0; j < 4; ++j) {
      float4 v = *(const float4*)(src + (size_t)r * NHID + c0 + j * 4);
      ld[r][c0 + j * 4 + 0] = v.x; ld[r][c0 + j * 4 + 1] = v.y;
      ld[r][c0 + j * 4 + 2] = v.z; ld[r][c0 + j * 4 + 3] = v.w;
    }
    __syncthreads();
    int n = threadIdx.x >> 2, kq = threadIdx.x & 3;
    unsigned short tmp[16];
#pragma unroll
    for (int j = 0; j < 16; ++j) tmp[j] = f2bf(ld[kq * 16 + j][n]);
    unsigned short* dst = Wt + ((size_t)hd * 64 + n) * NFEAT + kt * 64 + kq * 16;
    ((uint4*)dst)[0] = *(uint4*)tmp;
    ((uint4*)dst)[1] = *(uint4*)(tmp + 8);
  } else {
    for (int e = threadIdx.x; e < NFEAT * NCLASS; e += 256) {
      int n = e & 15, k = e >> 4;
      Wt2[(size_t)n * NFEAT + k] = f2bf(Wo[(size_t)k * NCLASS + n]);
    }
    if (threadIdx.x < NHEADS) tmax1u[threadIdx.x] = 0u;  // mono(-inf)
    if (threadIdx.x == 0) *tmax2u = 0u;
  }
}

// ---------------------------------------------------------------------------
// K1: MFMA bf16 GEMM h = x @ Wh per head, 128x64 tile, 4 waves, fused scores
// + per-head tmax. h written TRANSPOSED: h1T[hd][d][j] (bf16).
// ---------------------------------------------------------------------------
__global__ __launch_bounds__(256) void k_gemm_h(const unsigned short* __restrict__ xb,
                                                const unsigned short* __restrict__ Wt,
                                                const float* __restrict__ ah,
                                                unsigned short* __restrict__ h1T,
                                                float* __restrict__ ssrc,
                                                float* __restrict__ sdst,
                                                unsigned* __restrict__ tmax1u) {
  const int hd = blockIdx.y;
  const int i0 = blockIdx.x * 128;
  const int t = threadIdx.x;
  const int w = t >> 6, lane = t & 63;
  const int lr = lane & 15, kg = lane >> 4;
  const int wm = (w & 1) * 64, wn = (w >> 1) * 32;
  __shared__ uint4 Als[128][4];
  __shared__ uint4 Bls[64][4];
  __shared__ float sredS[128][2];
  __shared__ float sredD[128][2];
  const unsigned short* xrow = xb + (size_t)i0 * NFEAT;
  const unsigned short* wrow = Wt + (size_t)hd * 64 * NFEAT;

  f32x4 acc[4][2];
#pragma unroll
  for (int a = 0; a < 4; ++a)
#pragma unroll
    for (int b = 0; b < 2; ++b) acc[a][b] = (f32x4){0.f, 0.f, 0.f, 0.f};

  const int u0 = t, u1 = t + 256;
  const int ra0 = u0 >> 2, sa0 = ((u0 & 3) ^ (ra0 & 3)) * 8;
  const int ra1 = u1 >> 2, sa1 = ((u1 & 3) ^ (ra1 & 3)) * 8;
  const int rb0 = t >> 2,  sb0 = ((t & 3) ^ (rb0 & 3)) * 8;
  const int wbase = t & ~63;

  for (int k0 = 0; k0 < NFEAT; k0 += 32) {
    __builtin_amdgcn_global_load_lds(
        (const __attribute__((address_space(1))) void*)(xrow + (size_t)ra0 * NFEAT + k0 + sa0),
        (__attribute__((address_space(3))) void*)((uint4*)Als + wbase), 16, 0, 0);
    __builtin_amdgcn_global_load_lds(
        (const __attribute__((address_space(1))) void*)(xrow + (size_t)ra1 * NFEAT + k0 + sa1),
        (__attribute__((address_space(3))) void*)((uint4*)Als + 256 + wbase), 16, 0, 0);
    __builtin_amdgcn_global_load_lds(
        (const __attribute__((address_space(1))) void*)(wrow + (size_t)rb0 * NFEAT + k0 + sb0),
        (__attribute__((address_space(3))) void*)((uint4*)Bls + wbase), 16, 0, 0);
    __syncthreads();
    bf16x8 af[4], bfv[2];
#pragma unroll
    for (int mb = 0; mb < 4; ++mb) {
      int row = wm + mb * 16 + lr;
      af[mb] = __builtin_bit_cast(bf16x8, Als[row][kg ^ (row & 3)]);
    }
#pragma unroll
    for (int nb = 0; nb < 2; ++nb) {
      int col = wn + nb * 16 + lr;
      bfv[nb] = __builtin_bit_cast(bf16x8, Bls[col][kg ^ (col & 3)]);
    }
#pragma unroll
    for (int mb = 0; mb < 4; ++mb)
#pragma unroll
      for (int nb = 0; nb < 2; ++nb)
        acc[mb][nb] = __builtin_amdgcn_mfma_f32_16x16x32_bf16(af[mb], bfv[nb], acc[mb][nb], 0, 0, 0);
    __syncthreads();
  }

  unsigned short* hT = h1T + (size_t)hd * NHID * N;
#pragma unroll
  for (int mb = 0; mb < 4; ++mb)
#pragma unroll
    for (int nb = 0; nb < 2; ++nb) {
      int col = wn + nb * 16 + lr;
      int rbase = i0 + wm + mb * 16 + kg * 4;
      ushort4 o;
      o.x = f2bf(acc[mb][nb][0]); o.y = f2bf(acc[mb][nb][1]);
      o.z = f2bf(acc[mb][nb][2]); o.w = f2bf(acc[mb][nb][3]);
      *(ushort4*)(hT + (size_t)col * N + rbase) = o;
    }

  float aS[2], aD[2];
#pragma unroll
  for (int nb = 0; nb < 2; ++nb) {
    aS[nb] = ah[hd * 128 + wn + nb * 16 + lr];
    aD[nb] = ah[hd * 128 + 64 + wn + nb * 16 + lr];
  }
#pragma unroll
  for (int mb = 0; mb < 4; ++mb)
#pragma unroll
    for (int reg = 0; reg < 4; ++reg) {
      float ps = acc[mb][0][reg] * aS[0] + acc[mb][1][reg] * aS[1];
      float pd = acc[mb][0][reg] * aD[0] + acc[mb][1][reg] * aD[1];
#pragma unroll
      for (int m = 1; m < 16; m <<= 1) { ps += __shfl_xor(ps, m); pd += __shfl_xor(pd, m); }
      if (lr == 0) {
        int rl = wm + mb * 16 + kg * 4 + reg;
        sredS[rl][w >> 1] = ps;
        sredD[rl][w >> 1] = pd;
      }
    }
  __syncthreads();
  if (t < 128) {
    float vs = sredS[t][0] + sredS[t][1];
    float vd = sredD[t][0] + sredD[t][1];
    ssrc[(size_t)hd * N + i0 + t] = vs;
    sdst[(size_t)hd * N + i0 + t] = vd;
    float m = vd;
#pragma unroll
    for (int mk = 32; mk; mk >>= 1) m = fmaxf(m, __shfl_xor(m, mk));
    if ((t & 63) == 0) atomicMax(tmax1u + hd, mono(m));
  }
}

// ---------------------------------------------------------------------------
// K2a: layer-1 direct attention PARTIALS via MFMA, j-split. J1=128 (17.4 KB
// LDS) AND JSPL1=4 (grid 2048 = 8 blocks/CU): occupancy-driven.
// E-pack = truncation (proven). grid (N/64, NHEADS*JSPL1) x 256 thr.
// ---------------------------------------------------------------------------
__global__ __launch_bounds__(256) void k_attn1(const float* __restrict__ ssrc,
                                               const float* __restrict__ sdst,
                                               const unsigned short* __restrict__ h1T,
                                               const unsigned* __restrict__ tmax1u,
                                               float* __restrict__ pnum1,
                                               float* __restrict__ pz1) {
  __shared__ float tl[J1];                     // 0.5 KB
  __shared__ unsigned short hsT[64 * H1STR];   // 17.4 KB
  const int hd = blockIdx.y >> 2;
  const int jb = blockIdx.y & 3;
  const int tid = threadIdx.x, w = tid >> 6, lane = tid & 63;
  const int lr = lane & 15, kg = lane >> 4;
  const int row16 = blockIdx.x * 64 + w * 16;
  const unsigned short* hTh = h1T + (size_t)hd * NHID * N;
  const float* th = sdst + (size_t)hd * N;
  float tmax = unmono(tmax1u[hd]);
  float s = ssrc[(size_t)hd * N + row16 + lr];
  float v0 = s + tmax;
  float rowm = fmaxf(v0, ALPHA * v0);  // exact row max (monotone LeakyReLU)
  f32x4 acc[4];
#pragma unroll
  for (int nb = 0; nb < 4; ++nb) acc[nb] = (f32x4){0.f, 0.f, 0.f, 0.f};
  float zpart = 0.f;

  const int jc0 = jb * (N / J1 / JSPL1);
  for (int jc = jc0; jc < jc0 + N / J1 / JSPL1; ++jc) {
    if (tid < 32) *(float4*)(tl + tid * 4) = *(const float4*)(th + jc * J1 + tid * 4);
    // stage 64 rows x 128 bf16 (16 units of 8 per row)
#pragma unroll
    for (int rep = 0; rep < 4; ++rep) {
      int u = rep * 256 + tid;
      int r = u >> 4, cu = u & 15;
      *(uint4*)(hsT + r * H1STR + cu * 8) =
          *(const uint4*)(hTh + (size_t)r * N + jc * J1 + cu * 8);
    }
    __syncthreads();
#pragma unroll
    for (int c = 0; c < J1 / 32; ++c) {
      const float* tp = tl + c * 32 + kg * 8;
      float e[8];
#pragma unroll
      for (int m = 0; m < 8; ++m) {
        float v = s + tp[m];
        e[m] = __expf(fmaxf(v, ALPHA * v) - rowm);
        zpart += e[m];
      }
      unsigned pk[4];
#pragma unroll
      for (int p = 0; p < 4; ++p)
        pk[p] = (__float_as_uint(e[2 * p + 1]) & 0xFFFF0000u) |
                (__float_as_uint(e[2 * p]) >> 16);
      bf16x8 af = __builtin_bit_cast(bf16x8, *(uint4*)pk);
#pragma unroll
      for (int nb = 0; nb < 4; ++nb) {
        bf16x8 bf = __builtin_bit_cast(bf16x8,
            *(const uint4*)(hsT + (nb * 16 + lr) * H1STR + c * 32 + kg * 8));
        acc[nb] = __builtin_amdgcn_mfma_f32_16x16x32_bf16(af, bf, acc[nb], 0, 0, 0);
      }
    }
    __syncthreads();
  }
  // Z per row r lives in lanes {r, r+16, r+32, r+48}
  zpart += __shfl_xor(zpart, 16);
  zpart += __shfl_xor(zpart, 32);
  float* pn = pnum1 + ((size_t)(jb * NHEADS + hd) * N) * NHID;
#pragma unroll
  for (int reg = 0; reg < 4; ++reg) {
    int row = row16 + kg * 4 + reg;
#pragma unroll
    for (int nb = 0; nb < 4; ++nb)
      pn[(size_t)row * NHID + nb * 16 + lr] = acc[nb][reg];
  }
  if (lane < 16)
    pz1[(size_t)(jb * NHEADS + hd) * N + row16 + lane] = zpart;
}

// ---------------------------------------------------------------------------
// K2b: layer-1 combine partials + normalize + ELU -> xcb (bf16, head-major).
// grid (N/4, NHEADS) x 256 thr; wave = 1 row, lane = d.
// ---------------------------------------------------------------------------
__global__ __launch_bounds__(256) void k_attn1f(const float* __restrict__ pnum1,
                                                const float* __restrict__ pz1,
                                                unsigned short* __restrict__ xcb) {
  int hd = blockIdx.y;
  int w = threadIdx.x >> 6, lane = threadIdx.x & 63;
  int row = blockIdx.x * 4 + w;
  float nsum = 0.f, zsum = 0.f;
#pragma unroll
  for (int jb = 0; jb < JSPL1; ++jb) {
    nsum += pnum1[((size_t)(jb * NHEADS + hd) * N + row) * NHID + lane];
    zsum += pz1[(size_t)(jb * NHEADS + hd) * N + row];
  }
  float f = nsum / zsum;
  float e = f > 0.f ? f : expf(f) - 1.f;  // ELU
  xcb[(size_t)row * (NHEADS * NHID) + hd * NHID + lane] = f2bf(e);
}

// ---------------------------------------------------------------------------
// K3: h2 = xc @ Wo via MFMA + fused layer-2 scores + deterministic global
// tmax. h2 stored bf16.
// ---------------------------------------------------------------------------
__global__ __launch_bounds__(256) void k_gemm2(const unsigned short* __restrict__ xcb,
                                               const unsigned short* __restrict__ Wt2,
                                               const float* __restrict__ ao,
                                               unsigned short* __restrict__ h2b,
                                               float* __restrict__ ssrc,
                                               float* __restrict__ sdst,
                                               unsigned* __restrict__ tmax2u) {
  const int t = threadIdx.x;
  const int w = t >> 6, lane = t & 63;
  const int lr = lane & 15, kg = lane >> 4;
  const int i0 = blockIdx.x * 64 + w * 16;
  __shared__ float sd[64];
  f32x4 acc = (f32x4){0.f, 0.f, 0.f, 0.f};
  const unsigned short* arow = xcb + (size_t)(i0 + lr) * NFEAT;
  const unsigned short* brow = Wt2 + (size_t)lr * NFEAT;
#pragma unroll
  for (int k0 = 0; k0 < NFEAT; k0 += 32) {
    bf16x8 af = __builtin_bit_cast(bf16x8, *(const uint4*)(arow + k0 + kg * 8));
    bf16x8 bv = __builtin_bit_cast(bf16x8, *(const uint4*)(brow + k0 + kg * 8));
    acc = __builtin_amdgcn_mfma_f32_16x16x32_bf16(af, bv, acc, 0, 0, 0);
  }
  float aS = ao[lr], aD = ao[16 + lr];
#pragma unroll
  for (int reg = 0; reg < 4; ++reg) {
    int row = i0 + kg * 4 + reg;
    h2b[(size_t)row * NCLASS + lr] = f2bf(acc[reg]);
    float ps = acc[reg] * aS, pd = acc[reg] * aD;
#pragma unroll
    for (int m = 1; m < 16; m <<= 1) { ps += __shfl_xor(ps, m); pd += __shfl_xor(pd, m); }
    if (lr == 0) {
      ssrc[row] = ps;
      sdst[row] = pd;
      sd[w * 16 + kg * 4 + reg] = pd;
    }
  }
  __syncthreads();
  if (t < 64) {
    float v = sd[t];
#pragma unroll
    for (int m = 32; m; m >>= 1) v = fmaxf(v, __shfl_xor(v, m));
    if (t == 0) atomicMax(tmax2u, mono(v));
  }
}

// ---------------------------------------------------------------------------
// K4a: layer-2 attention partials via MFMA (unchanged, proven).
// ---------------------------------------------------------------------------
__global__ __launch_bounds__(256) void k_attn2p(const float* __restrict__ ssrc,
                                                const float* __restrict__ t,
                                                const unsigned short* __restrict__ h2b,
                                                const unsigned* __restrict__ tmax2u,
                                                float* __restrict__ pnum,
                                                float* __restrict__ pz) {
  __shared__ float tl[JLEN];                    // 2 KB
  __shared__ unsigned short hsT[16 * HSTR];     // 16.25 KB, transposed h2
  int tid = threadIdx.x;
  int jb = blockIdx.y;
  if (tid < 128) {
    int i4 = tid * 4;
    *(float4*)(tl + i4) = *(const float4*)(t + jb * JLEN + i4);
  }
#pragma unroll
  for (int rep = 0; rep < 2; ++rep) {
    int j = rep * 256 + tid;
    const uint4* src = (const uint4*)(h2b + (size_t)(jb * JLEN + j) * NCLASS);
    uint4 a = src[0], b = src[1];
    unsigned short v[16];
    *(uint4*)v = a; *(uint4*)(v + 8) = b;
#pragma unroll
    for (int c = 0; c < 16; ++c) hsT[c * HSTR + j] = v[c];
  }
  __syncthreads();
  int w = tid >> 6, lane = tid & 63;
  int lr = lane & 15, kg = lane >> 4;
  int ib = blockIdx.x * 64 + w * 16;
  float tmax = unmono(*tmax2u);
  float s = ssrc[ib + lr];
  float v0 = s + tmax;
  float rowm = fmaxf(v0, ALPHA * v0);
  f32x4 acc = (f32x4){0.f, 0.f, 0.f, 0.f};
  float zpart = 0.f;
#pragma unroll
  for (int c = 0; c < JLEN / 32; ++c) {
    const float* tp = tl + c * 32 + kg * 8;
    float e[8];
#pragma unroll
    for (int m = 0; m < 8; ++m) {
      float v = s + tp[m];
      e[m] = __expf(fmaxf(v, ALPHA * v) - rowm);
      zpart += e[m];
    }
    unsigned pk[4];
#pragma unroll
    for (int p = 0; p < 4; ++p)
      pk[p] = ((unsigned)f2bf(e[2 * p + 1]) << 16) | (unsigned)f2bf(e[2 * p]);
    bf16x8 af = __builtin_bit_cast(bf16x8, *(uint4*)pk);
    bf16x8 bf = __builtin_bit_cast(bf16x8,
        *(const uint4*)(hsT + lr * HSTR + c * 32 + kg * 8));
    acc = __builtin_amdgcn_mfma_f32_16x16x32_bf16(af, bf, acc, 0, 0, 0);
  }
  zpart += __shfl_xor(zpart, 16);
  zpart += __shfl_xor(zpart, 32);
#pragma unroll
  for (int reg = 0; reg < 4; ++reg)
    pnum[((size_t)jb * N + ib + kg * 4 + reg) * NCLASS + lr] = acc[reg];
  if (lane < 16) pz[(size_t)jb * N + ib + lane] = zpart;
}

// ---------------------------------------------------------------------------
// K4b: combine partials + ELU + log_softmax.
// ---------------------------------------------------------------------------
__global__ __launch_bounds__(256) void k_attn2f(const float* __restrict__ pnum,
                                                const float* __restrict__ pz,
                                                float* __restrict__ out) {
  int g = threadIdx.x >> 4, cl = threadIdx.x & 15;
  int i = blockIdx.x * 16 + g;
  float nsum = 0.f, zsum = 0.f;
#pragma unroll
  for (int jb = 0; jb < JSPL; ++jb) {
    nsum += pnum[((size_t)jb * N + i) * NCLASS + cl];
    zsum += pz[(size_t)jb * N + i];
  }
  float o = nsum / zsum;
  o = o > 0.f ? o : expf(o) - 1.f;  // ELU
  float mo = o;
#pragma unroll
  for (int mk = 1; mk < 16; mk <<= 1) mo = fmaxf(mo, __shfl_xor(mo, mk, 16));
  float sum = expf(o - mo);
#pragma unroll
  for (int mk = 1; mk < 16; mk <<= 1) sum += __shfl_xor(sum, mk, 16);
  out[(size_t)i * NCLASS + cl] = o - mo - logf(sum);
}

// ---------------------------------------------------------------------------
extern "C" void kernel_launch(void* const* d_in, const int* in_sizes, int n_in,
                              void* d_out, int out_size, void* d_ws, size_t ws_size,
                              hipStream_t stream) {
  const float* x  = (const float*)d_in[0];
  const float* Wh = (const float*)d_in[1];
  const float* ah = (const float*)d_in[2];
  const float* Wo = (const float*)d_in[3];
  const float* ao = (const float*)d_in[4];
  float* out = (float*)d_out;

  char* base = (char*)d_ws;
  size_t off = 0;
  auto alloc_f = [&](size_t n) -> float* {
    float* p = (float*)(base + off);
    off = (off + n * sizeof(float) + 255) & ~(size_t)255;
    return p;
  };
  auto alloc_i = [&](size_t n) -> int* {
    int* p = (int*)(base + off);
    off = (off + n * sizeof(int) + 255) & ~(size_t)255;
    return p;
  };
  auto alloc_u16 = [&](size_t n) -> unsigned short* {
    unsigned short* p = (unsigned short*)(base + off);
    off = (off + n * sizeof(unsigned short) + 255) & ~(size_t)255;
    return p;
  };

  unsigned short* xbf = alloc_u16((size_t)N * NFEAT);
  unsigned short* Wt  = alloc_u16((size_t)NHEADS * NHID * NFEAT);
  unsigned short* Wt2 = alloc_u16((size_t)NCLASS * NFEAT);
  unsigned short* h1T = alloc_u16((size_t)NHEADS * NHID * N);
  float* ssrc1 = alloc_f((size_t)NHEADS * N);
  float* sdst1 = alloc_f((size_t)NHEADS * N);
  unsigned* tmax1u = (unsigned*)alloc_i(NHEADS);
  float* pnum1 = alloc_f((size_t)JSPL1 * NHEADS * N * NHID);
  float* pz1   = alloc_f((size_t)JSPL1 * NHEADS * N);
  unsigned short* xcb = alloc_u16((size_t)N * NHEADS * NHID);
  unsigned short* h2b = alloc_u16((size_t)N * NCLASS);
  float* ssrc2 = alloc_f(N);
  float* sdst2 = alloc_f(N);
  unsigned* tmax2u = (unsigned*)alloc_i(1);
  float* pnum  = alloc_f((size_t)JSPL * N * NCLASS);
  float* pz    = alloc_f((size_t)JSPL * N);

  if (off > ws_size) return;

  hipLaunchKernelGGL(k_pack, dim3(2113), dim3(256), 0, stream, x, Wh, Wo, xbf, Wt, Wt2, tmax1u, tmax2u);

  // ---- Layer 1 (MFMA direct attention, j-split) ----
  hipLaunchKernelGGL(k_gemm_h, dim3(N / 128, NHEADS), dim3(256), 0, stream, xbf, Wt, ah, h1T, ssrc1, sdst1, tmax1u);
  hipLaunchKernelGGL(k_attn1, dim3(N / 64, NHEADS * JSPL1), dim3(256), 0, stream, ssrc1, sdst1, h1T, tmax1u, pnum1, pz1);
  hipLaunchKernelGGL(k_attn1f, dim3(N / 4, NHEADS), dim3(256), 0, stream, pnum1, pz1, xcb);

  // ---- Layer 2 (MFMA direct attention) ----
  hipLaunchKernelGGL(k_gemm2, dim3(N / 64), dim3(256), 0, stream, xcb, Wt2, ao, h2b, ssrc2, sdst2, tmax2u);
  hipLaunchKernelGGL(k_attn2p, dim3(N / 64, JSPL), dim3(256), 0, stream, ssrc2, sdst2, h2b, tmax2u, pnum, pz);
  hipLaunchKernelGGL(k_attn2f, dim3(N / 16), dim3(256), 0, stream, pnum, pz, out);
}

// Round 25
// 97.197 us; speedup vs baseline: 1.1491x; 1.0872x over previous
//
#include <hip/hip_runtime.h>
#include <math.h>

#define N 4096
#define NFEAT 512
#define NHID 64
#define NCLASS 16
#define NHEADS 8
#define ALPHA 0.2f
#define JSPL 8            // layer-2 j-split
#define JLEN (N / JSPL)   // 512
#define HSTR 520          // layer-2 hsT row stride (ushorts)
#define J1 256            // layer-1 j sub-chunk
#define H1STR 264         // layer-1 hsT row stride (ushorts)
#define JSPL1 2           // layer-1 j-split

typedef __attribute__((ext_vector_type(8))) short bf16x8;
typedef __attribute__((ext_vector_type(4))) float f32x4;

__device__ inline unsigned short f2bf(float f) {
  unsigned u = __float_as_uint(f);
  unsigned r = u + 0x7fffu + ((u >> 16) & 1u);  // RNE
  return (unsigned short)(r >> 16);
}
__device__ inline unsigned mono(float f) {
  unsigned u = __float_as_uint(f);
  return (u & 0x80000000u) ? ~u : (u | 0x80000000u);
}
__device__ inline float unmono(unsigned m) {
  return (m >> 31) ? __uint_as_float(m & 0x7FFFFFFFu) : __uint_as_float(~m);
}

// ---------------------------------------------------------------------------
// P0: pack. blocks [0,2048): x->bf16; [2048,2112): Wt=bf16(Wh^T);
// 2112: Wt2 + tmax inits.
// ---------------------------------------------------------------------------
__global__ __launch_bounds__(256) void k_pack(const float* __restrict__ x,
                                              const float* __restrict__ Wh,
                                              const float* __restrict__ Wo,
                                              unsigned short* __restrict__ xb,
                                              unsigned short* __restrict__ Wt,
                                              unsigned short* __restrict__ Wt2,
                                              unsigned* __restrict__ tmax1u,
                                              unsigned* __restrict__ tmax2u) {
  int b = blockIdx.x;
  if (b < 2048) {
    int i = (b * 256 + threadIdx.x) * 4;
    float4 v = *(const float4*)(x + i);
    ushort4 o;
    o.x = f2bf(v.x); o.y = f2bf(v.y); o.z = f2bf(v.z); o.w = f2bf(v.w);
    *(ushort4*)(xb + i) = o;
  } else if (b < 2112) {
    int idx = b - 2048;
    int kt = idx & 7, hd = idx >> 3;
    __shared__ float ld[64][65];
    const float* src = Wh + ((size_t)hd * NFEAT + kt * 64) * NHID;
    int r = threadIdx.x >> 2, c0 = (threadIdx.x & 3) * 16;
#pragma unroll
    for (int j = 0; j < 4; ++j) {
      float4 v = *(const float4*)(src + (size_t)r * NHID + c0 + j * 4);
      ld[r][c0 + j * 4 + 0] = v.x; ld[r][c0 + j * 4 + 1] = v.y;
      ld[r][c0 + j * 4 + 2] = v.z; ld[r][c0 + j * 4 + 3] = v.w;
    }
    __syncthreads();
    int n = threadIdx.x >> 2, kq = threadIdx.x & 3;
    unsigned short tmp[16];
#pragma unroll
    for (int j = 0; j < 16; ++j) tmp[j] = f2bf(ld[kq * 16 + j][n]);
    unsigned short* dst = Wt + ((size_t)hd * 64 + n) * NFEAT + kt * 64 + kq * 16;
    ((uint4*)dst)[0] = *(uint4*)tmp;
    ((uint4*)dst)[1] = *(uint4*)(tmp + 8);
  } else {
    for (int e = threadIdx.x; e < NFEAT * NCLASS; e += 256) {
      int n = e & 15, k = e >> 4;
      Wt2[(size_t)n * NFEAT + k] = f2bf(Wo[(size_t)k * NCLASS + n]);
    }
    if (threadIdx.x < NHEADS) tmax1u[threadIdx.x] = 0u;  // mono(-inf)
    if (threadIdx.x == 0) *tmax2u = 0u;
  }
}

// ---------------------------------------------------------------------------
// K1: MFMA bf16 GEMM h = x @ Wh per head, 128x64 tile, 4 waves, fused scores
// + per-head tmax. h written TRANSPOSED: h1T[hd][d][j] (bf16).
// ---------------------------------------------------------------------------
__global__ __launch_bounds__(256) void k_gemm_h(const unsigned short* __restrict__ xb,
                                                const unsigned short* __restrict__ Wt,
                                                const float* __restrict__ ah,
                                                unsigned short* __restrict__ h1T,
                                                float* __restrict__ ssrc,
                                                float* __restrict__ sdst,
                                                unsigned* __restrict__ tmax1u) {
  const int hd = blockIdx.y;
  const int i0 = blockIdx.x * 128;
  const int t = threadIdx.x;
  const int w = t >> 6, lane = t & 63;
  const int lr = lane & 15, kg = lane >> 4;
  const int wm = (w & 1) * 64, wn = (w >> 1) * 32;
  __shared__ uint4 Als[128][4];
  __shared__ uint4 Bls[64][4];
  __shared__ float sredS[128][2];
  __shared__ float sredD[128][2];
  const unsigned short* xrow = xb + (size_t)i0 * NFEAT;
  const unsigned short* wrow = Wt + (size_t)hd * 64 * NFEAT;

  f32x4 acc[4][2];
#pragma unroll
  for (int a = 0; a < 4; ++a)
#pragma unroll
    for (int b = 0; b < 2; ++b) acc[a][b] = (f32x4){0.f, 0.f, 0.f, 0.f};

  const int u0 = t, u1 = t + 256;
  const int ra0 = u0 >> 2, sa0 = ((u0 & 3) ^ (ra0 & 3)) * 8;
  const int ra1 = u1 >> 2, sa1 = ((u1 & 3) ^ (ra1 & 3)) * 8;
  const int rb0 = t >> 2,  sb0 = ((t & 3) ^ (rb0 & 3)) * 8;
  const int wbase = t & ~63;

  for (int k0 = 0; k0 < NFEAT; k0 += 32) {
    __builtin_amdgcn_global_load_lds(
        (const __attribute__((address_space(1))) void*)(xrow + (size_t)ra0 * NFEAT + k0 + sa0),
        (__attribute__((address_space(3))) void*)((uint4*)Als + wbase), 16, 0, 0);
    __builtin_amdgcn_global_load_lds(
        (const __attribute__((address_space(1))) void*)(xrow + (size_t)ra1 * NFEAT + k0 + sa1),
        (__attribute__((address_space(3))) void*)((uint4*)Als + 256 + wbase), 16, 0, 0);
    __builtin_amdgcn_global_load_lds(
        (const __attribute__((address_space(1))) void*)(wrow + (size_t)rb0 * NFEAT + k0 + sb0),
        (__attribute__((address_space(3))) void*)((uint4*)Bls + wbase), 16, 0, 0);
    __syncthreads();
    bf16x8 af[4], bfv[2];
#pragma unroll
    for (int mb = 0; mb < 4; ++mb) {
      int row = wm + mb * 16 + lr;
      af[mb] = __builtin_bit_cast(bf16x8, Als[row][kg ^ (row & 3)]);
    }
#pragma unroll
    for (int nb = 0; nb < 2; ++nb) {
      int col = wn + nb * 16 + lr;
      bfv[nb] = __builtin_bit_cast(bf16x8, Bls[col][kg ^ (col & 3)]);
    }
#pragma unroll
    for (int mb = 0; mb < 4; ++mb)
#pragma unroll
      for (int nb = 0; nb < 2; ++nb)
        acc[mb][nb] = __builtin_amdgcn_mfma_f32_16x16x32_bf16(af[mb], bfv[nb], acc[mb][nb], 0, 0, 0);
    __syncthreads();
  }

  unsigned short* hT = h1T + (size_t)hd * NHID * N;
#pragma unroll
  for (int mb = 0; mb < 4; ++mb)
#pragma unroll
    for (int nb = 0; nb < 2; ++nb) {
      int col = wn + nb * 16 + lr;
      int rbase = i0 + wm + mb * 16 + kg * 4;
      ushort4 o;
      o.x = f2bf(acc[mb][nb][0]); o.y = f2bf(acc[mb][nb][1]);
      o.z = f2bf(acc[mb][nb][2]); o.w = f2bf(acc[mb][nb][3]);
      *(ushort4*)(hT + (size_t)col * N + rbase) = o;
    }

  float aS[2], aD[2];
#pragma unroll
  for (int nb = 0; nb < 2; ++nb) {
    aS[nb] = ah[hd * 128 + wn + nb * 16 + lr];
    aD[nb] = ah[hd * 128 + 64 + wn + nb * 16 + lr];
  }
#pragma unroll
  for (int mb = 0; mb < 4; ++mb)
#pragma unroll
    for (int reg = 0; reg < 4; ++reg) {
      float ps = acc[mb][0][reg] * aS[0] + acc[mb][1][reg] * aS[1];
      float pd = acc[mb][0][reg] * aD[0] + acc[mb][1][reg] * aD[1];
#pragma unroll
      for (int m = 1; m < 16; m <<= 1) { ps += __shfl_xor(ps, m); pd += __shfl_xor(pd, m); }
      if (lr == 0) {
        int rl = wm + mb * 16 + kg * 4 + reg;
        sredS[rl][w >> 1] = ps;
        sredD[rl][w >> 1] = pd;
      }
    }
  __syncthreads();
  if (t < 128) {
    float vs = sredS[t][0] + sredS[t][1];
    float vd = sredD[t][0] + sredD[t][1];
    ssrc[(size_t)hd * N + i0 + t] = vs;
    sdst[(size_t)hd * N + i0 + t] = vd;
    float m = vd;
#pragma unroll
    for (int mk = 32; mk; mk >>= 1) m = fmaxf(m, __shfl_xor(m, mk));
    if ((t & 63) == 0) atomicMax(tmax1u + hd, mono(m));
  }
}

// ---------------------------------------------------------------------------
// K2a: layer-1 direct attention PARTIALS via MFMA, j-split (r21 structure).
// E-pack = truncation (proven). Z via MFMA against all-ones bf16 B fragment
// (removes 8 z-adds/c-iter + 2 end shuffles; accZ[reg] = Z of row kg*4+reg).
// grid (N/64, NHEADS*JSPL1) x 256 thr.
// ---------------------------------------------------------------------------
__global__ __launch_bounds__(256) void k_attn1(const float* __restrict__ ssrc,
                                               const float* __restrict__ sdst,
                                               const unsigned short* __restrict__ h1T,
                                               const unsigned* __restrict__ tmax1u,
                                               float* __restrict__ pnum1,
                                               float* __restrict__ pz1) {
  __shared__ float tl[J1];                     // 1 KB
  __shared__ unsigned short hsT[64 * H1STR];   // ~33.8 KB
  const int hd = blockIdx.y >> 1;
  const int jb = blockIdx.y & 1;
  const int tid = threadIdx.x, w = tid >> 6, lane = tid & 63;
  const int lr = lane & 15, kg = lane >> 4;
  const int row16 = blockIdx.x * 64 + w * 16;
  const unsigned short* hTh = h1T + (size_t)hd * NHID * N;
  const float* th = sdst + (size_t)hd * N;
  float tmax = unmono(tmax1u[hd]);
  float s = ssrc[(size_t)hd * N + row16 + lr];
  float v0 = s + tmax;
  float rowm = fmaxf(v0, ALPHA * v0);  // exact row max (monotone LeakyReLU)
  f32x4 acc[4];
#pragma unroll
  for (int nb = 0; nb < 4; ++nb) acc[nb] = (f32x4){0.f, 0.f, 0.f, 0.f};
  f32x4 accZ = (f32x4){0.f, 0.f, 0.f, 0.f};
  const uint4 onesu = (uint4){0x3F803F80u, 0x3F803F80u, 0x3F803F80u, 0x3F803F80u};
  const bf16x8 bones = __builtin_bit_cast(bf16x8, onesu);

  const int jc0 = jb * (N / J1 / JSPL1);
  for (int jc = jc0; jc < jc0 + N / J1 / JSPL1; ++jc) {
    if (tid < 64) *(float4*)(tl + tid * 4) = *(const float4*)(th + jc * J1 + tid * 4);
#pragma unroll
    for (int rep = 0; rep < 8; ++rep) {
      int u = rep * 256 + tid;
      int r = u >> 5, cu = u & 31;
      *(uint4*)(hsT + r * H1STR + cu * 8) =
          *(const uint4*)(hTh + (size_t)r * N + jc * J1 + cu * 8);
    }
    __syncthreads();
#pragma unroll
    for (int c = 0; c < J1 / 32; ++c) {
      const float* tp = tl + c * 32 + kg * 8;
      float e[8];
#pragma unroll
      for (int m = 0; m < 8; ++m) {
        float v = s + tp[m];
        e[m] = __expf(fmaxf(v, ALPHA * v) - rowm);
      }
      unsigned pk[4];
#pragma unroll
      for (int p = 0; p < 4; ++p)
        pk[p] = (__float_as_uint(e[2 * p + 1]) & 0xFFFF0000u) |
                (__float_as_uint(e[2 * p]) >> 16);
      bf16x8 af = __builtin_bit_cast(bf16x8, *(uint4*)pk);
      accZ = __builtin_amdgcn_mfma_f32_16x16x32_bf16(af, bones, accZ, 0, 0, 0);
#pragma unroll
      for (int nb = 0; nb < 4; ++nb) {
        bf16x8 bf = __builtin_bit_cast(bf16x8,
            *(const uint4*)(hsT + (nb * 16 + lr) * H1STR + c * 32 + kg * 8));
        acc[nb] = __builtin_amdgcn_mfma_f32_16x16x32_bf16(af, bf, acc[nb], 0, 0, 0);
      }
    }
    __syncthreads();
  }
  // accZ[reg] = Z of row kg*4+reg (same value in every column lane lr)
  float* pn = pnum1 + ((size_t)(jb * NHEADS + hd) * N) * NHID;
#pragma unroll
  for (int reg = 0; reg < 4; ++reg) {
    int row = row16 + kg * 4 + reg;
#pragma unroll
    for (int nb = 0; nb < 4; ++nb)
      pn[(size_t)row * NHID + nb * 16 + lr] = acc[nb][reg];
  }
  if (lr == 0) {
#pragma unroll
    for (int reg = 0; reg < 4; ++reg)
      pz1[(size_t)(jb * NHEADS + hd) * N + row16 + kg * 4 + reg] = accZ[reg];
  }
}

// ---------------------------------------------------------------------------
// K2b: layer-1 combine partials + normalize + ELU -> xcb (bf16, head-major).
// grid (N/4, NHEADS) x 256 thr; wave = 1 row, lane = d.
// ---------------------------------------------------------------------------
__global__ __launch_bounds__(256) void k_attn1f(const float* __restrict__ pnum1,
                                                const float* __restrict__ pz1,
                                                unsigned short* __restrict__ xcb) {
  int hd = blockIdx.y;
  int w = threadIdx.x >> 6, lane = threadIdx.x & 63;
  int row = blockIdx.x * 4 + w;
  float nsum = 0.f, zsum = 0.f;
#pragma unroll
  for (int jb = 0; jb < JSPL1; ++jb) {
    nsum += pnum1[((size_t)(jb * NHEADS + hd) * N + row) * NHID + lane];
    zsum += pz1[(size_t)(jb * NHEADS + hd) * N + row];
  }
  float f = nsum / zsum;
  float e = f > 0.f ? f : expf(f) - 1.f;  // ELU
  xcb[(size_t)row * (NHEADS * NHID) + hd * NHID + lane] = f2bf(e);
}

// ---------------------------------------------------------------------------
// K3: h2 = xc @ Wo via MFMA + fused layer-2 scores + deterministic global
// tmax. h2 stored bf16.
// ---------------------------------------------------------------------------
__global__ __launch_bounds__(256) void k_gemm2(const unsigned short* __restrict__ xcb,
                                               const unsigned short* __restrict__ Wt2,
                                               const float* __restrict__ ao,
                                               unsigned short* __restrict__ h2b,
                                               float* __restrict__ ssrc,
                                               float* __restrict__ sdst,
                                               unsigned* __restrict__ tmax2u) {
  const int t = threadIdx.x;
  const int w = t >> 6, lane = t & 63;
  const int lr = lane & 15, kg = lane >> 4;
  const int i0 = blockIdx.x * 64 + w * 16;
  __shared__ float sd[64];
  f32x4 acc = (f32x4){0.f, 0.f, 0.f, 0.f};
  const unsigned short* arow = xcb + (size_t)(i0 + lr) * NFEAT;
  const unsigned short* brow = Wt2 + (size_t)lr * NFEAT;
#pragma unroll
  for (int k0 = 0; k0 < NFEAT; k0 += 32) {
    bf16x8 af = __builtin_bit_cast(bf16x8, *(const uint4*)(arow + k0 + kg * 8));
    bf16x8 bv = __builtin_bit_cast(bf16x8, *(const uint4*)(brow + k0 + kg * 8));
    acc = __builtin_amdgcn_mfma_f32_16x16x32_bf16(af, bv, acc, 0, 0, 0);
  }
  float aS = ao[lr], aD = ao[16 + lr];
#pragma unroll
  for (int reg = 0; reg < 4; ++reg) {
    int row = i0 + kg * 4 + reg;
    h2b[(size_t)row * NCLASS + lr] = f2bf(acc[reg]);
    float ps = acc[reg] * aS, pd = acc[reg] * aD;
#pragma unroll
    for (int m = 1; m < 16; m <<= 1) { ps += __shfl_xor(ps, m); pd += __shfl_xor(pd, m); }
    if (lr == 0) {
      ssrc[row] = ps;
      sdst[row] = pd;
      sd[w * 16 + kg * 4 + reg] = pd;
    }
  }
  __syncthreads();
  if (t < 64) {
    float v = sd[t];
#pragma unroll
    for (int m = 32; m; m >>= 1) v = fmaxf(v, __shfl_xor(v, m));
    if (t == 0) atomicMax(tmax2u, mono(v));
  }
}

// ---------------------------------------------------------------------------
// K4a: layer-2 attention partials via MFMA (unchanged, proven).
// ---------------------------------------------------------------------------
__global__ __launch_bounds__(256) void k_attn2p(const float* __restrict__ ssrc,
                                                const float* __restrict__ t,
                                                const unsigned short* __restrict__ h2b,
                                                const unsigned* __restrict__ tmax2u,
                                                float* __restrict__ pnum,
                                                float* __restrict__ pz) {
  __shared__ float tl[JLEN];                    // 2 KB
  __shared__ unsigned short hsT[16 * HSTR];     // 16.25 KB, transposed h2
  int tid = threadIdx.x;
  int jb = blockIdx.y;
  if (tid < 128) {
    int i4 = tid * 4;
    *(float4*)(tl + i4) = *(const float4*)(t + jb * JLEN + i4);
  }
#pragma unroll
  for (int rep = 0; rep < 2; ++rep) {
    int j = rep * 256 + tid;
    const uint4* src = (const uint4*)(h2b + (size_t)(jb * JLEN + j) * NCLASS);
    uint4 a = src[0], b = src[1];
    unsigned short v[16];
    *(uint4*)v = a; *(uint4*)(v + 8) = b;
#pragma unroll
    for (int c = 0; c < 16; ++c) hsT[c * HSTR + j] = v[c];
  }
  __syncthreads();
  int w = tid >> 6, lane = tid & 63;
  int lr = lane & 15, kg = lane >> 4;
  int ib = blockIdx.x * 64 + w * 16;
  float tmax = unmono(*tmax2u);
  float s = ssrc[ib + lr];
  float v0 = s + tmax;
  float rowm = fmaxf(v0, ALPHA * v0);
  f32x4 acc = (f32x4){0.f, 0.f, 0.f, 0.f};
  float zpart = 0.f;
#pragma unroll
  for (int c = 0; c < JLEN / 32; ++c) {
    const float* tp = tl + c * 32 + kg * 8;
    float e[8];
#pragma unroll
    for (int m = 0; m < 8; ++m) {
      float v = s + tp[m];
      e[m] = __expf(fmaxf(v, ALPHA * v) - rowm);
      zpart += e[m];
    }
    unsigned pk[4];
#pragma unroll
    for (int p = 0; p < 4; ++p)
      pk[p] = ((unsigned)f2bf(e[2 * p + 1]) << 16) | (unsigned)f2bf(e[2 * p]);
    bf16x8 af = __builtin_bit_cast(bf16x8, *(uint4*)pk);
    bf16x8 bf = __builtin_bit_cast(bf16x8,
        *(const uint4*)(hsT + lr * HSTR + c * 32 + kg * 8));
    acc = __builtin_amdgcn_mfma_f32_16x16x32_bf16(af, bf, acc, 0, 0, 0);
  }
  zpart += __shfl_xor(zpart, 16);
  zpart += __shfl_xor(zpart, 32);
#pragma unroll
  for (int reg = 0; reg < 4; ++reg)
    pnum[((size_t)jb * N + ib + kg * 4 + reg) * NCLASS + lr] = acc[reg];
  if (lane < 16) pz[(size_t)jb * N + ib + lane] = zpart;
}

// ---------------------------------------------------------------------------
// K4b: combine partials + ELU + log_softmax.
// ---------------------------------------------------------------------------
__global__ __launch_bounds__(256) void k_attn2f(const float* __restrict__ pnum,
                                                const float* __restrict__ pz,
                                                float* __restrict__ out) {
  int g = threadIdx.x >> 4, cl = threadIdx.x & 15;
  int i = blockIdx.x * 16 + g;
  float nsum = 0.f, zsum = 0.f;
#pragma unroll
  for (int jb = 0; jb < JSPL; ++jb) {
    nsum += pnum[((size_t)jb * N + i) * NCLASS + cl];
    zsum += pz[(size_t)jb * N + i];
  }
  float o = nsum / zsum;
  o = o > 0.f ? o : expf(o) - 1.f;  // ELU
  float mo = o;
#pragma unroll
  for (int mk = 1; mk < 16; mk <<= 1) mo = fmaxf(mo, __shfl_xor(mo, mk, 16));
  float sum = expf(o - mo);
#pragma unroll
  for (int mk = 1; mk < 16; mk <<= 1) sum += __shfl_xor(sum, mk, 16);
  out[(size_t)i * NCLASS + cl] = o - mo - logf(sum);
}

// ---------------------------------------------------------------------------
extern "C" void kernel_launch(void* const* d_in, const int* in_sizes, int n_in,
                              void* d_out, int out_size, void* d_ws, size_t ws_size,
                              hipStream_t stream) {
  const float* x  = (const float*)d_in[0];
  const float* Wh = (const float*)d_in[1];
  const float* ah = (const float*)d_in[2];
  const float* Wo = (const float*)d_in[3];
  const float* ao = (const float*)d_in[4];
  float* out = (float*)d_out;

  char* base = (char*)d_ws;
  size_t off = 0;
  auto alloc_f = [&](size_t n) -> float* {
    float* p = (float*)(base + off);
    off = (off + n * sizeof(float) + 255) & ~(size_t)255;
    return p;
  };
  auto alloc_i = [&](size_t n) -> int* {
    int* p = (int*)(base + off);
    off = (off + n * sizeof(int) + 255) & ~(size_t)255;
    return p;
  };
  auto alloc_u16 = [&](size_t n) -> unsigned short* {
    unsigned short* p = (unsigned short*)(base + off);
    off = (off + n * sizeof(unsigned short) + 255) & ~(size_t)255;
    return p;
  };

  unsigned short* xbf = alloc_u16((size_t)N * NFEAT);
  unsigned short* Wt  = alloc_u16((size_t)NHEADS * NHID * NFEAT);
  unsigned short* Wt2 = alloc_u16((size_t)NCLASS * NFEAT);
  unsigned short* h1T = alloc_u16((size_t)NHEADS * NHID * N);
  float* ssrc1 = alloc_f((size_t)NHEADS * N);
  float* sdst1 = alloc_f((size_t)NHEADS * N);
  unsigned* tmax1u = (unsigned*)alloc_i(NHEADS);
  float* pnum1 = alloc_f((size_t)JSPL1 * NHEADS * N * NHID);
  float* pz1   = alloc_f((size_t)JSPL1 * NHEADS * N);
  unsigned short* xcb = alloc_u16((size_t)N * NHEADS * NHID);
  unsigned short* h2b = alloc_u16((size_t)N * NCLASS);
  float* ssrc2 = alloc_f(N);
  float* sdst2 = alloc_f(N);
  unsigned* tmax2u = (unsigned*)alloc_i(1);
  float* pnum  = alloc_f((size_t)JSPL * N * NCLASS);
  float* pz    = alloc_f((size_t)JSPL * N);

  if (off > ws_size) return;

  hipLaunchKernelGGL(k_pack, dim3(2113), dim3(256), 0, stream, x, Wh, Wo, xbf, Wt, Wt2, tmax1u, tmax2u);

  // ---- Layer 1 (MFMA direct attention, j-split) ----
  hipLaunchKernelGGL(k_gemm_h, dim3(N / 128, NHEADS), dim3(256), 0, stream, xbf, Wt, ah, h1T, ssrc1, sdst1, tmax1u);
  hipLaunchKernelGGL(k_attn1, dim3(N / 64, NHEADS * JSPL1), dim3(256), 0, stream, ssrc1, sdst1, h1T, tmax1u, pnum1, pz1);
  hipLaunchKernelGGL(k_attn1f, dim3(N / 4, NHEADS), dim3(256), 0, stream, pnum1, pz1, xcb);

  // ---- Layer 2 (MFMA direct attention) ----
  hipLaunchKernelGGL(k_gemm2, dim3(N / 64), dim3(256), 0, stream, xcb, Wt2, ao, h2b, ssrc2, sdst2, tmax2u);
  hipLaunchKernelGGL(k_attn2p, dim3(N / 64, JSPL), dim3(256), 0, stream, ssrc2, sdst2, h2b, tmax2u, pnum, pz);
  hipLaunchKernelGGL(k_attn2f, dim3(N / 16), dim3(256), 0, stream, pnum, pz, out);
}